// Round 1
// baseline (1745.911 us; speedup 1.0000x reference)
//
#include <hip/hip_runtime.h>
#include <math.h>

#define N1 50000
#define F_IN 128
#define E1 1000000
#define Bg 10
#define NPG 5000
#define N2 199
#define E2 4000
#define KSEL 50
#define LN_EPS 1e-5f

// ---------------- CSR build ----------------
__global__ void k_zero(int* __restrict__ p, int n) {
  int i = blockIdx.x * 256 + threadIdx.x;
  if (i < n) p[i] = 0;
}

__global__ void k_hist(const int* __restrict__ dst, int* __restrict__ cnt, int E) {
  int e = blockIdx.x * 256 + threadIdx.x;
  if (e < E) atomicAdd(&cnt[dst[e]], 1);
}

// single-block exclusive scan: rp[0]=0, rp[i+1]=sum(cnt[0..i])
__global__ void k_scan(const int* __restrict__ cnt, int* __restrict__ rp, int n) {
  __shared__ int sh[1024];
  __shared__ int carry;
  int t = threadIdx.x;
  if (t == 0) { carry = 0; rp[0] = 0; }
  for (int base = 0; base < n; base += 1024) {
    __syncthreads();
    int v = (base + t < n) ? cnt[base + t] : 0;
    sh[t] = v;
    __syncthreads();
    for (int off = 1; off < 1024; off <<= 1) {
      int add = (t >= off) ? sh[t - off] : 0;
      __syncthreads();
      sh[t] += add;
      __syncthreads();
    }
    if (base + t < n) rp[base + t + 1] = carry + sh[t];
    __syncthreads();
    if (t == 0) carry += sh[1023];
  }
}

__global__ void k_scatter(const int* __restrict__ src, const int* __restrict__ dst,
                          const int* __restrict__ rp, int* __restrict__ cur,
                          int* __restrict__ srcs, int E) {
  int e = blockIdx.x * 256 + threadIdx.x;
  if (e < E) {
    int d = dst[e];
    int pos = atomicAdd(&cur[d], 1);
    srcs[rp[d] + pos] = src[e];
  }
}

// ---------------- mean aggregation ----------------
// block 256 = 2 nodes x 128 features; coalesced 512B row gathers
__global__ void k_aggregate(const float* __restrict__ x, const int* __restrict__ rp,
                            const int* __restrict__ srcs, float* __restrict__ mean, int n) {
  int f = threadIdx.x & 127;
  int node = blockIdx.x * 2 + (threadIdx.x >> 7);
  if (node >= n) return;
  int s = rp[node], e = rp[node + 1];
  float acc = 0.f;
  for (int i = s; i < e; i++) {
    int src = srcs[i];
    acc += x[(size_t)src * F_IN + f];
  }
  int cnt = e - s;
  mean[(size_t)node * F_IN + f] = acc / (float)(cnt > 0 ? cnt : 1);
}

// ---------------- SAGE linear: out = relu(mean @ wl^T + bl + xin @ wr^T) ----------------
// K fixed = 128. O = out features (128 or 64). NN nodes per thread.
template <int O, int NN>
__global__ void k_sage_lin(const float* __restrict__ xin,   // [n,128]
                           const float* __restrict__ mean,  // [n,128]
                           const float* __restrict__ wl,    // [O,128]
                           const float* __restrict__ bl,    // [O]
                           const float* __restrict__ wr,    // [O,128]
                           float* __restrict__ out,         // [n,O]
                           int n) {
  constexpr int G = 256 / O;
  constexpr int NB = G * NN;
  constexpr int TK = 32;
  __shared__ float s_wl[TK][O];
  __shared__ float s_wr[TK][O];
  __shared__ float s_a[NB][TK];
  __shared__ float s_x[NB][TK];
  int t = threadIdx.x;
  int j = t % O;
  int g = t / O;
  int nodeBase = blockIdx.x * NB;
  float acc[NN];
#pragma unroll
  for (int i = 0; i < NN; i++) acc[i] = 0.f;
  for (int k0 = 0; k0 < 128; k0 += TK) {
    __syncthreads();
    for (int idx = t; idx < TK * O; idx += 256) {
      int kk = idx / O, jj = idx % O;
      s_wl[kk][jj] = wl[jj * 128 + k0 + kk];
      s_wr[kk][jj] = wr[jj * 128 + k0 + kk];
    }
    for (int idx = t; idx < NB * TK; idx += 256) {
      int ni = idx / TK, kk = idx % TK;
      int node = nodeBase + ni;
      float av = 0.f, xv = 0.f;
      if (node < n) {
        av = mean[(size_t)node * 128 + k0 + kk];
        xv = xin[(size_t)node * 128 + k0 + kk];
      }
      s_a[ni][kk] = av;
      s_x[ni][kk] = xv;
    }
    __syncthreads();
#pragma unroll
    for (int kk = 0; kk < TK; kk++) {
      float wlv = s_wl[kk][j];
      float wrv = s_wr[kk][j];
#pragma unroll
      for (int i = 0; i < NN; i++) {
        int ni = g * NN + i;
        acc[i] = fmaf(s_a[ni][kk], wlv, acc[i]);
        acc[i] = fmaf(s_x[ni][kk], wrv, acc[i]);
      }
    }
  }
  float bias = bl[j];
#pragma unroll
  for (int i = 0; i < NN; i++) {
    int node = nodeBase + g * NN + i;
    if (node < n) {
      float v = acc[i] + bias;
      out[(size_t)node * O + j] = v > 0.f ? v : 0.f;
    }
  }
}

// ---------------- score: dist(out1[n], out2[198]) ----------------
__global__ void k_score(const float* __restrict__ out1, const float* __restrict__ out2,
                        float* __restrict__ scores, int n) {
  int lane = threadIdx.x & 63;
  int node = blockIdx.x * 4 + (threadIdx.x >> 6);
  if (node >= n) return;
  float a = out1[(size_t)node * 64 + lane];
  float bb = out2[198 * 64 + lane];
  float a2 = a * a, b2 = bb * bb, ab = a * bb;
  for (int off = 32; off; off >>= 1) {
    a2 += __shfl_xor(a2, off);
    b2 += __shfl_xor(b2, off);
    ab += __shfl_xor(ab, off);
  }
  if (lane == 0) {
    float d2 = a2 + b2 - 2.f * ab;
    scores[node] = sqrtf(fmaxf(d2, 0.f));
  }
}

// ---------------- stable top-50 per graph (desc, ties -> smaller index) ----------------
__global__ void k_topk(const float* __restrict__ scores, int* __restrict__ sel) {
  __shared__ float s[NPG];
  __shared__ float wbv[4];
  __shared__ int wbi[4];
  int b = blockIdx.x, t = threadIdx.x;  // 256 threads
  for (int i = t; i < NPG; i += 256) s[i] = scores[b * NPG + i];
  for (int r = 0; r < KSEL; r++) {
    __syncthreads();
    float bv = -INFINITY;
    int bi = 0x7fffffff;
    for (int i = t; i < NPG; i += 256) {
      float v = s[i];
      if (v > bv || (v == bv && i < bi)) { bv = v; bi = i; }
    }
    for (int off = 32; off; off >>= 1) {
      float ov = __shfl_down(bv, off);
      int oi = __shfl_down(bi, off);
      if (ov > bv || (ov == bv && oi < bi)) { bv = ov; bi = oi; }
    }
    if ((t & 63) == 0) { wbv[t >> 6] = bv; wbi[t >> 6] = bi; }
    __syncthreads();
    if (t == 0) {
      for (int w = 1; w < 4; w++)
        if (wbv[w] > bv || (wbv[w] == bv && wbi[w] < bi)) { bv = wbv[w]; bi = wbi[w]; }
      sel[b * KSEL + r] = b * NPG + bi;
      s[bi] = -INFINITY;
    }
  }
}

// ---------------- dist rows for selected nodes: D[500][199] ----------------
__global__ void k_dist_rows(const float* __restrict__ out1, const float* __restrict__ out2,
                            const int* __restrict__ sel, float* __restrict__ D) {
  __shared__ float arow[64];
  int i = blockIdx.x;  // 0..499
  int t = threadIdx.x; // 256
  int node = sel[i];
  if (t < 64) arow[t] = out1[(size_t)node * 64 + t];
  __syncthreads();
  float a2 = 0.f;
#pragma unroll
  for (int f = 0; f < 64; f++) a2 = fmaf(arow[f], arow[f], a2);
  for (int nn = t; nn < N2; nn += 256) {
    float dot = 0.f, b2 = 0.f;
#pragma unroll 8
    for (int f = 0; f < 64; f++) {
      float bv = out2[nn * 64 + f];
      dot = fmaf(arow[f], bv, dot);
      b2 = fmaf(bv, bv, b2);
    }
    float d2 = a2 + b2 - 2.f * dot;
    D[i * N2 + nn] = sqrtf(fmaxf(d2, 0.f));
  }
}

// ---------------- fc1 + LN + relu: [10, 9950] -> [10, 128] ----------------
__global__ void k_fc1(const float* __restrict__ D, const float* __restrict__ w,
                      const float* __restrict__ bias, const float* __restrict__ g,
                      const float* __restrict__ be, float* __restrict__ h1out) {
  constexpr int M = KSEL * N2;  // 9950
  __shared__ __align__(16) float sdb[M];
  __shared__ float wsum[2];
  int b = blockIdx.x, t = threadIdx.x;  // 128 threads
  for (int m = t; m < M; m += 128) sdb[m] = D[b * M + m];
  __syncthreads();
  float acc = bias[t];
  const float2* w2p = (const float2*)(w + (size_t)t * M);
  const float2* s2 = (const float2*)sdb;
  for (int m = 0; m < M / 2; m++) {
    float2 wv = w2p[m];
    float2 sv = s2[m];
    acc = fmaf(sv.x, wv.x, acc);
    acc = fmaf(sv.y, wv.y, acc);
  }
  int lane = t & 63, wv_ = t >> 6;
  float ssum = acc;
  for (int off = 32; off; off >>= 1) ssum += __shfl_xor(ssum, off);
  if (lane == 0) wsum[wv_] = ssum;
  __syncthreads();
  float mu = (wsum[0] + wsum[1]) / 128.f;
  __syncthreads();
  float d = acc - mu;
  float vv = d * d;
  for (int off = 32; off; off >>= 1) vv += __shfl_xor(vv, off);
  if (lane == 0) wsum[wv_] = vv;
  __syncthreads();
  float var = (wsum[0] + wsum[1]) / 128.f;
  float r = rsqrtf(var + LN_EPS);
  float h = d * r * g[t] + be[t];
  h1out[b * 128 + t] = h > 0.f ? h : 0.f;
}

// ---------------- fc2 + LN + relu + fc3 + sigmoid ----------------
__global__ void k_fc23(const float* __restrict__ h1, const float* __restrict__ w2,
                       const float* __restrict__ b2v, const float* __restrict__ g2,
                       const float* __restrict__ be2, const float* __restrict__ w3,
                       const float* __restrict__ b3, float* __restrict__ out) {
  int b = blockIdx.x, j = threadIdx.x;  // 64 threads = 1 wave
  __shared__ float sh1[128];
  sh1[j] = h1[b * 128 + j];
  sh1[j + 64] = h1[b * 128 + j + 64];
  __syncthreads();
  float acc = b2v[j];
#pragma unroll 8
  for (int k = 0; k < 128; k++) acc = fmaf(sh1[k], w2[j * 128 + k], acc);
  float s = acc;
  for (int off = 32; off; off >>= 1) s += __shfl_xor(s, off);
  float mu = s * (1.f / 64.f);
  float d = acc - mu;
  float vv = d * d;
  for (int off = 32; off; off >>= 1) vv += __shfl_xor(vv, off);
  float r = rsqrtf(vv * (1.f / 64.f) + LN_EPS);
  float h = d * r * g2[j] + be2[j];
  h = h > 0.f ? h : 0.f;
  float p = h * w3[j];
  for (int off = 32; off; off >>= 1) p += __shfl_xor(p, off);
  if (j == 0) out[b] = 1.f / (1.f + expf(-(p + b3[0])));
}

extern "C" void kernel_launch(void* const* d_in, const int* in_sizes, int n_in,
                              void* d_out, int out_size, void* d_ws, size_t ws_size,
                              hipStream_t stream) {
  const float* x1 = (const float*)d_in[0];
  const int* ei1 = (const int*)d_in[1];
  // d_in[2] = batch1 (unused: equal-size contiguous graphs)
  const float* x2 = (const float*)d_in[3];
  const int* ei2 = (const int*)d_in[4];
  const float* w1l = (const float*)d_in[5];
  const float* b1l = (const float*)d_in[6];
  const float* w1r = (const float*)d_in[7];
  const float* w2l = (const float*)d_in[8];
  const float* b2l = (const float*)d_in[9];
  const float* w2r = (const float*)d_in[10];
  const float* fc1w = (const float*)d_in[11];
  const float* fc1b = (const float*)d_in[12];
  const float* ln1g = (const float*)d_in[13];
  const float* ln1b = (const float*)d_in[14];
  const float* fc2w = (const float*)d_in[15];
  const float* fc2b = (const float*)d_in[16];
  const float* ln2g = (const float*)d_in[17];
  const float* ln2b = (const float*)d_in[18];
  const float* fc3w = (const float*)d_in[19];
  const float* fc3b = (const float*)d_in[20];
  float* out = (float*)d_out;

  char* p = (char*)d_ws;
  auto alloc = [&](size_t bytes) {
    char* r = p;
    p += (bytes + 255) & ~(size_t)255;
    return r;
  };
  int* rp1 = (int*)alloc((N1 + 1) * 4);
  int* cur1 = (int*)alloc(N1 * 4);
  int* srcs1 = (int*)alloc((size_t)E1 * 4);
  int* rp2 = (int*)alloc((N2 + 1) * 4);
  int* cur2 = (int*)alloc(N2 * 4);
  int* srcs2 = (int*)alloc(E2 * 4);
  float* bufMean = (float*)alloc((size_t)N1 * 128 * 4);
  float* bufH = (float*)alloc((size_t)N1 * 128 * 4);
  float* out1b = (float*)alloc((size_t)N1 * 64 * 4);
  float* mean2 = (float*)alloc((size_t)N2 * 128 * 4);
  float* h2g = (float*)alloc((size_t)N2 * 128 * 4);
  float* out2b = (float*)alloc((size_t)N2 * 64 * 4);
  float* scores = (float*)alloc((size_t)N1 * 4);
  int* sel = (int*)alloc(Bg * KSEL * 4);
  float* Dm = (float*)alloc((size_t)Bg * KSEL * N2 * 4);
  float* h1m = (float*)alloc(Bg * 128 * 4);

  // ---- CSR graph1 ----
  k_zero<<<(N1 + 255) / 256, 256, 0, stream>>>(cur1, N1);
  k_hist<<<(E1 + 255) / 256, 256, 0, stream>>>(ei1 + E1, cur1, E1);
  k_scan<<<1, 1024, 0, stream>>>(cur1, rp1, N1);
  k_zero<<<(N1 + 255) / 256, 256, 0, stream>>>(cur1, N1);
  k_scatter<<<(E1 + 255) / 256, 256, 0, stream>>>(ei1, ei1 + E1, rp1, cur1, srcs1, E1);
  // ---- CSR graph2 ----
  k_zero<<<1, 256, 0, stream>>>(cur2, N2);
  k_hist<<<(E2 + 255) / 256, 256, 0, stream>>>(ei2 + E2, cur2, E2);
  k_scan<<<1, 1024, 0, stream>>>(cur2, rp2, N2);
  k_zero<<<1, 256, 0, stream>>>(cur2, N2);
  k_scatter<<<(E2 + 255) / 256, 256, 0, stream>>>(ei2, ei2 + E2, rp2, cur2, srcs2, E2);
  // ---- GNN graph1 ----
  k_aggregate<<<(N1 + 1) / 2, 256, 0, stream>>>(x1, rp1, srcs1, bufMean, N1);
  k_sage_lin<128, 8><<<(N1 + 15) / 16, 256, 0, stream>>>(x1, bufMean, w1l, b1l, w1r, bufH, N1);
  k_aggregate<<<(N1 + 1) / 2, 256, 0, stream>>>(bufH, rp1, srcs1, bufMean, N1);
  k_sage_lin<64, 8><<<(N1 + 31) / 32, 256, 0, stream>>>(bufH, bufMean, w2l, b2l, w2r, out1b, N1);
  // ---- GNN graph2 ----
  k_aggregate<<<(N2 + 1) / 2, 256, 0, stream>>>(x2, rp2, srcs2, mean2, N2);
  k_sage_lin<128, 8><<<(N2 + 15) / 16, 256, 0, stream>>>(x2, mean2, w1l, b1l, w1r, h2g, N2);
  k_aggregate<<<(N2 + 1) / 2, 256, 0, stream>>>(h2g, rp2, srcs2, mean2, N2);
  k_sage_lin<64, 8><<<(N2 + 31) / 32, 256, 0, stream>>>(h2g, mean2, w2l, b2l, w2r, out2b, N2);
  // ---- head ----
  k_score<<<(N1 + 3) / 4, 256, 0, stream>>>(out1b, out2b, scores, N1);
  k_topk<<<Bg, 256, 0, stream>>>(scores, sel);
  k_dist_rows<<<Bg * KSEL, 256, 0, stream>>>(out1b, out2b, sel, Dm);
  k_fc1<<<Bg, 128, 0, stream>>>(Dm, fc1w, fc1b, ln1g, ln1b, h1m);
  k_fc23<<<Bg, 64, 0, stream>>>(h1m, fc2w, fc2b, ln2g, ln2b, fc3w, fc3b, out);
}

// Round 2
// 1252.091 us; speedup vs baseline: 1.3944x; 1.3944x over previous
//
#include <hip/hip_runtime.h>
#include <math.h>

#define N1 50000
#define F_IN 128
#define E1 1000000
#define Bg 10
#define NPG 5000
#define N2 199
#define E2 4000
#define KSEL 50
#define LN_EPS 1e-5f

// ---------------- CSR build ----------------
__global__ void k_zero(int* __restrict__ p, int n) {
  int i = blockIdx.x * 256 + threadIdx.x;
  if (i < n) p[i] = 0;
}

__global__ void k_hist(const int* __restrict__ dst, int* __restrict__ cnt, int E) {
  int e = blockIdx.x * 256 + threadIdx.x;
  if (e < E) atomicAdd(&cnt[dst[e]], 1);
}

// single-block exclusive scan: rp[0]=0, rp[i+1]=sum(cnt[0..i])
__global__ void k_scan(const int* __restrict__ cnt, int* __restrict__ rp, int n) {
  __shared__ int sh[1024];
  __shared__ int carry;
  int t = threadIdx.x;
  if (t == 0) { carry = 0; rp[0] = 0; }
  for (int base = 0; base < n; base += 1024) {
    __syncthreads();
    int v = (base + t < n) ? cnt[base + t] : 0;
    sh[t] = v;
    __syncthreads();
    for (int off = 1; off < 1024; off <<= 1) {
      int add = (t >= off) ? sh[t - off] : 0;
      __syncthreads();
      sh[t] += add;
      __syncthreads();
    }
    if (base + t < n) rp[base + t + 1] = carry + sh[t];
    __syncthreads();
    if (t == 0) carry += sh[1023];
  }
}

__global__ void k_scatter(const int* __restrict__ src, const int* __restrict__ dst,
                          const int* __restrict__ rp, int* __restrict__ cur,
                          int* __restrict__ srcs, int E) {
  int e = blockIdx.x * 256 + threadIdx.x;
  if (e < E) {
    int d = dst[e];
    int pos = atomicAdd(&cur[d], 1);
    srcs[rp[d] + pos] = src[e];
  }
}

// ---------------- mean aggregation ----------------
// block 256 = 2 nodes x 128 features; coalesced 512B row gathers
__global__ void k_aggregate(const float* __restrict__ x, const int* __restrict__ rp,
                            const int* __restrict__ srcs, float* __restrict__ mean, int n) {
  int f = threadIdx.x & 127;
  int node = blockIdx.x * 2 + (threadIdx.x >> 7);
  if (node >= n) return;
  int s = rp[node], e = rp[node + 1];
  float acc = 0.f;
  for (int i = s; i < e; i++) {
    int src = srcs[i];
    acc += x[(size_t)src * F_IN + f];
  }
  int cnt = e - s;
  mean[(size_t)node * F_IN + f] = acc / (float)(cnt > 0 ? cnt : 1);
}

// ---------------- SAGE linear: out = relu(mean @ wl^T + bl + xin @ wr^T) ----------------
// K fixed = 128. O = out features (128 or 64). NN nodes per thread.
template <int O, int NN>
__global__ void k_sage_lin(const float* __restrict__ xin,   // [n,128]
                           const float* __restrict__ mean,  // [n,128]
                           const float* __restrict__ wl,    // [O,128]
                           const float* __restrict__ bl,    // [O]
                           const float* __restrict__ wr,    // [O,128]
                           float* __restrict__ out,         // [n,O]
                           int n) {
  constexpr int G = 256 / O;
  constexpr int NB = G * NN;
  constexpr int TK = 32;
  __shared__ float s_wl[TK][O];
  __shared__ float s_wr[TK][O];
  __shared__ float s_a[NB][TK];
  __shared__ float s_x[NB][TK];
  int t = threadIdx.x;
  int j = t % O;
  int g = t / O;
  int nodeBase = blockIdx.x * NB;
  float acc[NN];
#pragma unroll
  for (int i = 0; i < NN; i++) acc[i] = 0.f;
  for (int k0 = 0; k0 < 128; k0 += TK) {
    __syncthreads();
    for (int idx = t; idx < TK * O; idx += 256) {
      int kk = idx / O, jj = idx % O;
      s_wl[kk][jj] = wl[jj * 128 + k0 + kk];
      s_wr[kk][jj] = wr[jj * 128 + k0 + kk];
    }
    for (int idx = t; idx < NB * TK; idx += 256) {
      int ni = idx / TK, kk = idx % TK;
      int node = nodeBase + ni;
      float av = 0.f, xv = 0.f;
      if (node < n) {
        av = mean[(size_t)node * 128 + k0 + kk];
        xv = xin[(size_t)node * 128 + k0 + kk];
      }
      s_a[ni][kk] = av;
      s_x[ni][kk] = xv;
    }
    __syncthreads();
#pragma unroll
    for (int kk = 0; kk < TK; kk++) {
      float wlv = s_wl[kk][j];
      float wrv = s_wr[kk][j];
#pragma unroll
      for (int i = 0; i < NN; i++) {
        int ni = g * NN + i;
        acc[i] = fmaf(s_a[ni][kk], wlv, acc[i]);
        acc[i] = fmaf(s_x[ni][kk], wrv, acc[i]);
      }
    }
  }
  float bias = bl[j];
#pragma unroll
  for (int i = 0; i < NN; i++) {
    int node = nodeBase + g * NN + i;
    if (node < n) {
      float v = acc[i] + bias;
      out[(size_t)node * O + j] = v > 0.f ? v : 0.f;
    }
  }
}

// ---------------- score: dist(out1[n], out2[198]) ----------------
__global__ void k_score(const float* __restrict__ out1, const float* __restrict__ out2,
                        float* __restrict__ scores, int n) {
  int lane = threadIdx.x & 63;
  int node = blockIdx.x * 4 + (threadIdx.x >> 6);
  if (node >= n) return;
  float a = out1[(size_t)node * 64 + lane];
  float bb = out2[198 * 64 + lane];
  float a2 = a * a, b2 = bb * bb, ab = a * bb;
  for (int off = 32; off; off >>= 1) {
    a2 += __shfl_xor(a2, off);
    b2 += __shfl_xor(b2, off);
    ab += __shfl_xor(ab, off);
  }
  if (lane == 0) {
    float d2 = a2 + b2 - 2.f * ab;
    scores[node] = sqrtf(fmaxf(d2, 0.f));
  }
}

// ---------------- stable top-50 per graph (desc, ties -> smaller index) ----------------
__global__ void k_topk(const float* __restrict__ scores, int* __restrict__ sel) {
  __shared__ float s[NPG];
  __shared__ float wbv[4];
  __shared__ int wbi[4];
  int b = blockIdx.x, t = threadIdx.x;  // 256 threads
  for (int i = t; i < NPG; i += 256) s[i] = scores[b * NPG + i];
  for (int r = 0; r < KSEL; r++) {
    __syncthreads();
    float bv = -INFINITY;
    int bi = 0x7fffffff;
    for (int i = t; i < NPG; i += 256) {
      float v = s[i];
      if (v > bv || (v == bv && i < bi)) { bv = v; bi = i; }
    }
    for (int off = 32; off; off >>= 1) {
      float ov = __shfl_down(bv, off);
      int oi = __shfl_down(bi, off);
      if (ov > bv || (ov == bv && oi < bi)) { bv = ov; bi = oi; }
    }
    if ((t & 63) == 0) { wbv[t >> 6] = bv; wbi[t >> 6] = bi; }
    __syncthreads();
    if (t == 0) {
      for (int w = 1; w < 4; w++)
        if (wbv[w] > bv || (wbv[w] == bv && wbi[w] < bi)) { bv = wbv[w]; bi = wbi[w]; }
      sel[b * KSEL + r] = b * NPG + bi;
      s[bi] = -INFINITY;
    }
  }
}

// ---------------- dist rows for selected nodes: D[500][199] ----------------
__global__ void k_dist_rows(const float* __restrict__ out1, const float* __restrict__ out2,
                            const int* __restrict__ sel, float* __restrict__ D) {
  __shared__ float arow[64];
  int i = blockIdx.x;  // 0..499
  int t = threadIdx.x; // 256
  int node = sel[i];
  if (t < 64) arow[t] = out1[(size_t)node * 64 + t];
  __syncthreads();
  float a2 = 0.f;
#pragma unroll
  for (int f = 0; f < 64; f++) a2 = fmaf(arow[f], arow[f], a2);
  for (int nn = t; nn < N2; nn += 256) {
    float dot = 0.f, b2 = 0.f;
#pragma unroll 8
    for (int f = 0; f < 64; f++) {
      float bv = out2[nn * 64 + f];
      dot = fmaf(arow[f], bv, dot);
      b2 = fmaf(bv, bv, b2);
    }
    float d2 = a2 + b2 - 2.f * dot;
    D[i * N2 + nn] = sqrtf(fmaxf(d2, 0.f));
  }
}

// ---------------- fc1 dot: one block per (b, j) output scalar ----------------
// h1pre[b*128+j] = dot(D[b,:], w[j,:])  over M=9950, coalesced float2 loads
__global__ void k_fc1_dot(const float* __restrict__ D, const float* __restrict__ w,
                          float* __restrict__ h1pre) {
  constexpr int M = KSEL * N2;   // 9950
  constexpr int M2 = M / 2;      // 4975 float2
  int b = blockIdx.x >> 7;       // 0..9
  int j = blockIdx.x & 127;      // 0..127
  int t = threadIdx.x;           // 256
  const float2* wp = (const float2*)(w + (size_t)j * M);
  const float2* dp = (const float2*)(D + (size_t)b * M);
  float acc = 0.f;
  for (int m = t; m < M2; m += 256) {
    float2 wv = wp[m];
    float2 dv = dp[m];
    acc = fmaf(dv.x, wv.x, acc);
    acc = fmaf(dv.y, wv.y, acc);
  }
  for (int off = 32; off; off >>= 1) acc += __shfl_xor(acc, off);
  __shared__ float ws_[4];
  int lane = t & 63, wv_ = t >> 6;
  if (lane == 0) ws_[wv_] = acc;
  __syncthreads();
  if (t == 0) h1pre[b * 128 + j] = ws_[0] + ws_[1] + ws_[2] + ws_[3];
}

// ---------------- fc1 LN + relu: [10,128] ----------------
__global__ void k_fc1_ln(const float* __restrict__ h1pre, const float* __restrict__ bias,
                         const float* __restrict__ g, const float* __restrict__ be,
                         float* __restrict__ h1out) {
  __shared__ float wsum[2];
  int b = blockIdx.x, t = threadIdx.x;  // 128 threads
  float acc = h1pre[b * 128 + t] + bias[t];
  int lane = t & 63, wv_ = t >> 6;
  float ssum = acc;
  for (int off = 32; off; off >>= 1) ssum += __shfl_xor(ssum, off);
  if (lane == 0) wsum[wv_] = ssum;
  __syncthreads();
  float mu = (wsum[0] + wsum[1]) / 128.f;
  __syncthreads();
  float d = acc - mu;
  float vv = d * d;
  for (int off = 32; off; off >>= 1) vv += __shfl_xor(vv, off);
  if (lane == 0) wsum[wv_] = vv;
  __syncthreads();
  float var = (wsum[0] + wsum[1]) / 128.f;
  float r = rsqrtf(var + LN_EPS);
  float h = d * r * g[t] + be[t];
  h1out[b * 128 + t] = h > 0.f ? h : 0.f;
}

// ---------------- fc2 + LN + relu + fc3 + sigmoid ----------------
__global__ void k_fc23(const float* __restrict__ h1, const float* __restrict__ w2,
                       const float* __restrict__ b2v, const float* __restrict__ g2,
                       const float* __restrict__ be2, const float* __restrict__ w3,
                       const float* __restrict__ b3, float* __restrict__ out) {
  int b = blockIdx.x, j = threadIdx.x;  // 64 threads = 1 wave
  __shared__ float sh1[128];
  sh1[j] = h1[b * 128 + j];
  sh1[j + 64] = h1[b * 128 + j + 64];
  __syncthreads();
  float acc = b2v[j];
#pragma unroll 8
  for (int k = 0; k < 128; k++) acc = fmaf(sh1[k], w2[j * 128 + k], acc);
  float s = acc;
  for (int off = 32; off; off >>= 1) s += __shfl_xor(s, off);
  float mu = s * (1.f / 64.f);
  float d = acc - mu;
  float vv = d * d;
  for (int off = 32; off; off >>= 1) vv += __shfl_xor(vv, off);
  float r = rsqrtf(vv * (1.f / 64.f) + LN_EPS);
  float h = d * r * g2[j] + be2[j];
  h = h > 0.f ? h : 0.f;
  float p = h * w3[j];
  for (int off = 32; off; off >>= 1) p += __shfl_xor(p, off);
  if (j == 0) out[b] = 1.f / (1.f + expf(-(p + b3[0])));
}

extern "C" void kernel_launch(void* const* d_in, const int* in_sizes, int n_in,
                              void* d_out, int out_size, void* d_ws, size_t ws_size,
                              hipStream_t stream) {
  const float* x1 = (const float*)d_in[0];
  const int* ei1 = (const int*)d_in[1];
  // d_in[2] = batch1 (unused: equal-size contiguous graphs)
  const float* x2 = (const float*)d_in[3];
  const int* ei2 = (const int*)d_in[4];
  const float* w1l = (const float*)d_in[5];
  const float* b1l = (const float*)d_in[6];
  const float* w1r = (const float*)d_in[7];
  const float* w2l = (const float*)d_in[8];
  const float* b2l = (const float*)d_in[9];
  const float* w2r = (const float*)d_in[10];
  const float* fc1w = (const float*)d_in[11];
  const float* fc1b = (const float*)d_in[12];
  const float* ln1g = (const float*)d_in[13];
  const float* ln1b = (const float*)d_in[14];
  const float* fc2w = (const float*)d_in[15];
  const float* fc2b = (const float*)d_in[16];
  const float* ln2g = (const float*)d_in[17];
  const float* ln2b = (const float*)d_in[18];
  const float* fc3w = (const float*)d_in[19];
  const float* fc3b = (const float*)d_in[20];
  float* out = (float*)d_out;

  char* p = (char*)d_ws;
  auto alloc = [&](size_t bytes) {
    char* r = p;
    p += (bytes + 255) & ~(size_t)255;
    return r;
  };
  int* rp1 = (int*)alloc((N1 + 1) * 4);
  int* cur1 = (int*)alloc(N1 * 4);
  int* srcs1 = (int*)alloc((size_t)E1 * 4);
  int* rp2 = (int*)alloc((N2 + 1) * 4);
  int* cur2 = (int*)alloc(N2 * 4);
  int* srcs2 = (int*)alloc(E2 * 4);
  float* bufMean = (float*)alloc((size_t)N1 * 128 * 4);
  float* bufH = (float*)alloc((size_t)N1 * 128 * 4);
  float* out1b = (float*)alloc((size_t)N1 * 64 * 4);
  float* mean2 = (float*)alloc((size_t)N2 * 128 * 4);
  float* h2g = (float*)alloc((size_t)N2 * 128 * 4);
  float* out2b = (float*)alloc((size_t)N2 * 64 * 4);
  float* scores = (float*)alloc((size_t)N1 * 4);
  int* sel = (int*)alloc(Bg * KSEL * 4);
  float* Dm = (float*)alloc((size_t)Bg * KSEL * N2 * 4);
  float* h1pre = (float*)alloc(Bg * 128 * 4);
  float* h1m = (float*)alloc(Bg * 128 * 4);

  // ---- CSR graph1 ----
  k_zero<<<(N1 + 255) / 256, 256, 0, stream>>>(cur1, N1);
  k_hist<<<(E1 + 255) / 256, 256, 0, stream>>>(ei1 + E1, cur1, E1);
  k_scan<<<1, 1024, 0, stream>>>(cur1, rp1, N1);
  k_zero<<<(N1 + 255) / 256, 256, 0, stream>>>(cur1, N1);
  k_scatter<<<(E1 + 255) / 256, 256, 0, stream>>>(ei1, ei1 + E1, rp1, cur1, srcs1, E1);
  // ---- CSR graph2 ----
  k_zero<<<1, 256, 0, stream>>>(cur2, N2);
  k_hist<<<(E2 + 255) / 256, 256, 0, stream>>>(ei2 + E2, cur2, E2);
  k_scan<<<1, 1024, 0, stream>>>(cur2, rp2, N2);
  k_zero<<<1, 256, 0, stream>>>(cur2, N2);
  k_scatter<<<(E2 + 255) / 256, 256, 0, stream>>>(ei2, ei2 + E2, rp2, cur2, srcs2, E2);
  // ---- GNN graph1 ----
  k_aggregate<<<(N1 + 1) / 2, 256, 0, stream>>>(x1, rp1, srcs1, bufMean, N1);
  k_sage_lin<128, 8><<<(N1 + 15) / 16, 256, 0, stream>>>(x1, bufMean, w1l, b1l, w1r, bufH, N1);
  k_aggregate<<<(N1 + 1) / 2, 256, 0, stream>>>(bufH, rp1, srcs1, bufMean, N1);
  k_sage_lin<64, 8><<<(N1 + 31) / 32, 256, 0, stream>>>(bufH, bufMean, w2l, b2l, w2r, out1b, N1);
  // ---- GNN graph2 ----
  k_aggregate<<<(N2 + 1) / 2, 256, 0, stream>>>(x2, rp2, srcs2, mean2, N2);
  k_sage_lin<128, 8><<<(N2 + 15) / 16, 256, 0, stream>>>(x2, mean2, w1l, b1l, w1r, h2g, N2);
  k_aggregate<<<(N2 + 1) / 2, 256, 0, stream>>>(h2g, rp2, srcs2, mean2, N2);
  k_sage_lin<64, 8><<<(N2 + 31) / 32, 256, 0, stream>>>(h2g, mean2, w2l, b2l, w2r, out2b, N2);
  // ---- head ----
  k_score<<<(N1 + 3) / 4, 256, 0, stream>>>(out1b, out2b, scores, N1);
  k_topk<<<Bg, 256, 0, stream>>>(scores, sel);
  k_dist_rows<<<Bg * KSEL, 256, 0, stream>>>(out1b, out2b, sel, Dm);
  k_fc1_dot<<<Bg * 128, 256, 0, stream>>>(Dm, fc1w, h1pre);
  k_fc1_ln<<<Bg, 128, 0, stream>>>(h1pre, fc1b, ln1g, ln1b, h1m);
  k_fc23<<<Bg, 64, 0, stream>>>(h1m, fc2w, fc2b, ln2g, ln2b, fc3w, fc3b, out);
}

// Round 3
// 1013.555 us; speedup vs baseline: 1.7226x; 1.2353x over previous
//
#include <hip/hip_runtime.h>
#include <math.h>

#define N1 50000
#define F_IN 128
#define E1 1000000
#define Bg 10
#define NPG 5000
#define N2 199
#define E2 4000
#define KSEL 50
#define LN_EPS 1e-5f

// ---------------- CSR build ----------------
__global__ void k_zero(int* __restrict__ p, int n) {
  int i = blockIdx.x * 256 + threadIdx.x;
  if (i < n) p[i] = 0;
}

__global__ void k_hist(const int* __restrict__ dst, int* __restrict__ cnt, int E) {
  int e = blockIdx.x * 256 + threadIdx.x;
  if (e < E) atomicAdd(&cnt[dst[e]], 1);
}

// single-block exclusive scan: rp[0]=0, rp[i+1]=sum(cnt[0..i])
__global__ void k_scan(const int* __restrict__ cnt, int* __restrict__ rp, int n) {
  __shared__ int sh[1024];
  __shared__ int carry;
  int t = threadIdx.x;
  if (t == 0) { carry = 0; rp[0] = 0; }
  for (int base = 0; base < n; base += 1024) {
    __syncthreads();
    int v = (base + t < n) ? cnt[base + t] : 0;
    sh[t] = v;
    __syncthreads();
    for (int off = 1; off < 1024; off <<= 1) {
      int add = (t >= off) ? sh[t - off] : 0;
      __syncthreads();
      sh[t] += add;
      __syncthreads();
    }
    if (base + t < n) rp[base + t + 1] = carry + sh[t];
    __syncthreads();
    if (t == 0) carry += sh[1023];
  }
}

__global__ void k_scatter(const int* __restrict__ src, const int* __restrict__ dst,
                          const int* __restrict__ rp, int* __restrict__ cur,
                          int* __restrict__ srcs, int E) {
  int e = blockIdx.x * 256 + threadIdx.x;
  if (e < E) {
    int d = dst[e];
    int pos = atomicAdd(&cur[d], 1);
    srcs[rp[d] + pos] = src[e];
  }
}

// ---------------- mean aggregation ----------------
// block 256 = 2 nodes x 128 features; coalesced 512B row gathers
__global__ void k_aggregate(const float* __restrict__ x, const int* __restrict__ rp,
                            const int* __restrict__ srcs, float* __restrict__ mean, int n) {
  int f = threadIdx.x & 127;
  int node = blockIdx.x * 2 + (threadIdx.x >> 7);
  if (node >= n) return;
  int s = rp[node], e = rp[node + 1];
  float acc = 0.f;
  for (int i = s; i < e; i++) {
    int src = srcs[i];
    acc += x[(size_t)src * F_IN + f];
  }
  int cnt = e - s;
  mean[(size_t)node * F_IN + f] = acc / (float)(cnt > 0 ? cnt : 1);
}

// ---------------- SAGE linear as register-tiled GEMM ----------------
// out[n,O] = relu( mean @ wl^T + bl + xin @ wr^T ), K = 128 per phase.
// Block tile: 128 nodes x O outputs; 256 threads as 16x16; micro-tile 8 x (O/16).
template <int O>
__global__ __launch_bounds__(256) void k_sage_gemm(
    const float* __restrict__ xin,   // [n,128]
    const float* __restrict__ mean,  // [n,128]
    const float* __restrict__ wl,    // [O,128]
    const float* __restrict__ bl,    // [O]
    const float* __restrict__ wr,    // [O,128]
    float* __restrict__ out,         // [n,O]
    int n) {
  constexpr int TM = 128, TK = 32;
  constexpr int SA = TM + 4;  // row stride (floats), 16B-aligned rows
  constexpr int SW = O + 4;
  constexpr int NJ = O / 16;  // 8 (O=128) or 4 (O=64)
  __shared__ float s_a[TK][SA];
  __shared__ float s_w[TK][SW];
  int t = threadIdx.x;
  int tx = t & 15, ty = t >> 4;
  int m0 = blockIdx.x * TM;
  int sub = t >> 3;          // 0..31
  int kv = (t & 7) << 2;     // 0,4,..,28

  float acc[8][NJ];
#pragma unroll
  for (int i = 0; i < 8; i++)
#pragma unroll
    for (int j = 0; j < NJ; j++) acc[i][j] = 0.f;

  for (int ph = 0; ph < 2; ph++) {
    const float* A = ph ? xin : mean;
    const float* W = ph ? wr : wl;
    for (int k0 = 0; k0 < 128; k0 += TK) {
      __syncthreads();
      // stage A tile (128 nodes x 32 k), transposed into s_a[k][node]
#pragma unroll
      for (int p = 0; p < 4; p++) {
        int node = m0 + p * 32 + sub;
        float4 v = make_float4(0.f, 0.f, 0.f, 0.f);
        if (node < n) v = *(const float4*)&A[(size_t)node * 128 + k0 + kv];
        int col = p * 32 + sub;
        s_a[kv + 0][col] = v.x;
        s_a[kv + 1][col] = v.y;
        s_a[kv + 2][col] = v.z;
        s_a[kv + 3][col] = v.w;
      }
      // stage W tile (O x 32 k), transposed into s_w[k][j]
#pragma unroll
      for (int p = 0; p < O / 32; p++) {
        int j = p * 32 + sub;
        float4 v = *(const float4*)&W[(size_t)j * 128 + k0 + kv];
        s_w[kv + 0][j] = v.x;
        s_w[kv + 1][j] = v.y;
        s_w[kv + 2][j] = v.z;
        s_w[kv + 3][j] = v.w;
      }
      __syncthreads();
#pragma unroll 8
      for (int kk = 0; kk < TK; kk++) {
        float4 a0 = *(const float4*)&s_a[kk][ty * 8];
        float4 a1 = *(const float4*)&s_a[kk][ty * 8 + 4];
        float av[8] = {a0.x, a0.y, a0.z, a0.w, a1.x, a1.y, a1.z, a1.w};
        float wv[NJ];
        {
          float4 w0 = *(const float4*)&s_w[kk][tx * NJ];
          wv[0] = w0.x; wv[1] = w0.y; wv[2] = w0.z; wv[3] = w0.w;
          if constexpr (NJ == 8) {
            float4 w1 = *(const float4*)&s_w[kk][tx * NJ + 4];
            wv[4] = w1.x; wv[5] = w1.y; wv[6] = w1.z; wv[7] = w1.w;
          }
        }
#pragma unroll
        for (int i = 0; i < 8; i++)
#pragma unroll
          for (int j = 0; j < NJ; j++) acc[i][j] = fmaf(av[i], wv[j], acc[i][j]);
      }
    }
  }
  // epilogue: bias + relu, coalesced float4 stores
  float bj[NJ];
#pragma unroll
  for (int j = 0; j < NJ; j++) bj[j] = bl[tx * NJ + j];
#pragma unroll
  for (int i = 0; i < 8; i++) {
    int node = m0 + ty * 8 + i;
    if (node < n) {
#pragma unroll
      for (int q = 0; q < NJ; q += 4) {
        float4 o;
        float v0 = acc[i][q + 0] + bj[q + 0];
        float v1 = acc[i][q + 1] + bj[q + 1];
        float v2 = acc[i][q + 2] + bj[q + 2];
        float v3 = acc[i][q + 3] + bj[q + 3];
        o.x = v0 > 0.f ? v0 : 0.f;
        o.y = v1 > 0.f ? v1 : 0.f;
        o.z = v2 > 0.f ? v2 : 0.f;
        o.w = v3 > 0.f ? v3 : 0.f;
        *(float4*)&out[(size_t)node * O + tx * NJ + q] = o;
      }
    }
  }
}

// ---------------- score: dist(out1[n], out2[198]) ----------------
__global__ void k_score(const float* __restrict__ out1, const float* __restrict__ out2,
                        float* __restrict__ scores, int n) {
  int lane = threadIdx.x & 63;
  int node = blockIdx.x * 4 + (threadIdx.x >> 6);
  if (node >= n) return;
  float a = out1[(size_t)node * 64 + lane];
  float bb = out2[198 * 64 + lane];
  float a2 = a * a, b2 = bb * bb, ab = a * bb;
  for (int off = 32; off; off >>= 1) {
    a2 += __shfl_xor(a2, off);
    b2 += __shfl_xor(b2, off);
    ab += __shfl_xor(ab, off);
  }
  if (lane == 0) {
    float d2 = a2 + b2 - 2.f * ab;
    scores[node] = sqrtf(fmaxf(d2, 0.f));
  }
}

// ---------------- stable top-50 per graph (desc, ties -> smaller index) ----------------
__global__ void k_topk(const float* __restrict__ scores, int* __restrict__ sel) {
  __shared__ float s[NPG];
  __shared__ float wbv[4];
  __shared__ int wbi[4];
  int b = blockIdx.x, t = threadIdx.x;  // 256 threads
  for (int i = t; i < NPG; i += 256) s[i] = scores[b * NPG + i];
  for (int r = 0; r < KSEL; r++) {
    __syncthreads();
    float bv = -INFINITY;
    int bi = 0x7fffffff;
    for (int i = t; i < NPG; i += 256) {
      float v = s[i];
      if (v > bv || (v == bv && i < bi)) { bv = v; bi = i; }
    }
    for (int off = 32; off; off >>= 1) {
      float ov = __shfl_down(bv, off);
      int oi = __shfl_down(bi, off);
      if (ov > bv || (ov == bv && oi < bi)) { bv = ov; bi = oi; }
    }
    if ((t & 63) == 0) { wbv[t >> 6] = bv; wbi[t >> 6] = bi; }
    __syncthreads();
    if (t == 0) {
      for (int w = 1; w < 4; w++)
        if (wbv[w] > bv || (wbv[w] == bv && wbi[w] < bi)) { bv = wbv[w]; bi = wbi[w]; }
      sel[b * KSEL + r] = b * NPG + bi;
      s[bi] = -INFINITY;
    }
  }
}

// ---------------- dist rows for selected nodes: D[500][199] ----------------
__global__ void k_dist_rows(const float* __restrict__ out1, const float* __restrict__ out2,
                            const int* __restrict__ sel, float* __restrict__ D) {
  __shared__ float arow[64];
  int i = blockIdx.x;  // 0..499
  int t = threadIdx.x; // 256
  int node = sel[i];
  if (t < 64) arow[t] = out1[(size_t)node * 64 + t];
  __syncthreads();
  float a2 = 0.f;
#pragma unroll
  for (int f = 0; f < 64; f++) a2 = fmaf(arow[f], arow[f], a2);
  for (int nn = t; nn < N2; nn += 256) {
    float dot = 0.f, b2 = 0.f;
#pragma unroll 8
    for (int f = 0; f < 64; f++) {
      float bv = out2[nn * 64 + f];
      dot = fmaf(arow[f], bv, dot);
      b2 = fmaf(bv, bv, b2);
    }
    float d2 = a2 + b2 - 2.f * dot;
    D[i * N2 + nn] = sqrtf(fmaxf(d2, 0.f));
  }
}

// ---------------- fc1 dot: one block per (b, j) output scalar ----------------
__global__ void k_fc1_dot(const float* __restrict__ D, const float* __restrict__ w,
                          float* __restrict__ h1pre) {
  constexpr int M = KSEL * N2;   // 9950
  constexpr int M2 = M / 2;      // 4975 float2
  int b = blockIdx.x >> 7;       // 0..9
  int j = blockIdx.x & 127;      // 0..127
  int t = threadIdx.x;           // 256
  const float2* wp = (const float2*)(w + (size_t)j * M);
  const float2* dp = (const float2*)(D + (size_t)b * M);
  float acc = 0.f;
  for (int m = t; m < M2; m += 256) {
    float2 wv = wp[m];
    float2 dv = dp[m];
    acc = fmaf(dv.x, wv.x, acc);
    acc = fmaf(dv.y, wv.y, acc);
  }
  for (int off = 32; off; off >>= 1) acc += __shfl_xor(acc, off);
  __shared__ float ws_[4];
  int lane = t & 63, wv_ = t >> 6;
  if (lane == 0) ws_[wv_] = acc;
  __syncthreads();
  if (t == 0) h1pre[b * 128 + j] = ws_[0] + ws_[1] + ws_[2] + ws_[3];
}

// ---------------- fc1 LN + relu: [10,128] ----------------
__global__ void k_fc1_ln(const float* __restrict__ h1pre, const float* __restrict__ bias,
                         const float* __restrict__ g, const float* __restrict__ be,
                         float* __restrict__ h1out) {
  __shared__ float wsum[2];
  int b = blockIdx.x, t = threadIdx.x;  // 128 threads
  float acc = h1pre[b * 128 + t] + bias[t];
  int lane = t & 63, wv_ = t >> 6;
  float ssum = acc;
  for (int off = 32; off; off >>= 1) ssum += __shfl_xor(ssum, off);
  if (lane == 0) wsum[wv_] = ssum;
  __syncthreads();
  float mu = (wsum[0] + wsum[1]) / 128.f;
  __syncthreads();
  float d = acc - mu;
  float vv = d * d;
  for (int off = 32; off; off >>= 1) vv += __shfl_xor(vv, off);
  if (lane == 0) wsum[wv_] = vv;
  __syncthreads();
  float var = (wsum[0] + wsum[1]) / 128.f;
  float r = rsqrtf(var + LN_EPS);
  float h = d * r * g[t] + be[t];
  h1out[b * 128 + t] = h > 0.f ? h : 0.f;
}

// ---------------- fc2 + LN + relu + fc3 + sigmoid ----------------
__global__ void k_fc23(const float* __restrict__ h1, const float* __restrict__ w2,
                       const float* __restrict__ b2v, const float* __restrict__ g2,
                       const float* __restrict__ be2, const float* __restrict__ w3,
                       const float* __restrict__ b3, float* __restrict__ out) {
  int b = blockIdx.x, j = threadIdx.x;  // 64 threads = 1 wave
  __shared__ float sh1[128];
  sh1[j] = h1[b * 128 + j];
  sh1[j + 64] = h1[b * 128 + j + 64];
  __syncthreads();
  float acc = b2v[j];
#pragma unroll 8
  for (int k = 0; k < 128; k++) acc = fmaf(sh1[k], w2[j * 128 + k], acc);
  float s = acc;
  for (int off = 32; off; off >>= 1) s += __shfl_xor(s, off);
  float mu = s * (1.f / 64.f);
  float d = acc - mu;
  float vv = d * d;
  for (int off = 32; off; off >>= 1) vv += __shfl_xor(vv, off);
  float r = rsqrtf(vv * (1.f / 64.f) + LN_EPS);
  float h = d * r * g2[j] + be2[j];
  h = h > 0.f ? h : 0.f;
  float p = h * w3[j];
  for (int off = 32; off; off >>= 1) p += __shfl_xor(p, off);
  if (j == 0) out[b] = 1.f / (1.f + expf(-(p + b3[0])));
}

extern "C" void kernel_launch(void* const* d_in, const int* in_sizes, int n_in,
                              void* d_out, int out_size, void* d_ws, size_t ws_size,
                              hipStream_t stream) {
  const float* x1 = (const float*)d_in[0];
  const int* ei1 = (const int*)d_in[1];
  // d_in[2] = batch1 (unused: equal-size contiguous graphs)
  const float* x2 = (const float*)d_in[3];
  const int* ei2 = (const int*)d_in[4];
  const float* w1l = (const float*)d_in[5];
  const float* b1l = (const float*)d_in[6];
  const float* w1r = (const float*)d_in[7];
  const float* w2l = (const float*)d_in[8];
  const float* b2l = (const float*)d_in[9];
  const float* w2r = (const float*)d_in[10];
  const float* fc1w = (const float*)d_in[11];
  const float* fc1b = (const float*)d_in[12];
  const float* ln1g = (const float*)d_in[13];
  const float* ln1b = (const float*)d_in[14];
  const float* fc2w = (const float*)d_in[15];
  const float* fc2b = (const float*)d_in[16];
  const float* ln2g = (const float*)d_in[17];
  const float* ln2b = (const float*)d_in[18];
  const float* fc3w = (const float*)d_in[19];
  const float* fc3b = (const float*)d_in[20];
  float* out = (float*)d_out;

  char* p = (char*)d_ws;
  auto alloc = [&](size_t bytes) {
    char* r = p;
    p += (bytes + 255) & ~(size_t)255;
    return r;
  };
  int* rp1 = (int*)alloc((N1 + 1) * 4);
  int* cur1 = (int*)alloc(N1 * 4);
  int* srcs1 = (int*)alloc((size_t)E1 * 4);
  int* rp2 = (int*)alloc((N2 + 1) * 4);
  int* cur2 = (int*)alloc(N2 * 4);
  int* srcs2 = (int*)alloc(E2 * 4);
  float* bufMean = (float*)alloc((size_t)N1 * 128 * 4);
  float* bufH = (float*)alloc((size_t)N1 * 128 * 4);
  float* out1b = (float*)alloc((size_t)N1 * 64 * 4);
  float* mean2 = (float*)alloc((size_t)N2 * 128 * 4);
  float* h2g = (float*)alloc((size_t)N2 * 128 * 4);
  float* out2b = (float*)alloc((size_t)N2 * 64 * 4);
  float* scores = (float*)alloc((size_t)N1 * 4);
  int* sel = (int*)alloc(Bg * KSEL * 4);
  float* Dm = (float*)alloc((size_t)Bg * KSEL * N2 * 4);
  float* h1pre = (float*)alloc(Bg * 128 * 4);
  float* h1m = (float*)alloc(Bg * 128 * 4);

  // ---- CSR graph1 ----
  k_zero<<<(N1 + 255) / 256, 256, 0, stream>>>(cur1, N1);
  k_hist<<<(E1 + 255) / 256, 256, 0, stream>>>(ei1 + E1, cur1, E1);
  k_scan<<<1, 1024, 0, stream>>>(cur1, rp1, N1);
  k_zero<<<(N1 + 255) / 256, 256, 0, stream>>>(cur1, N1);
  k_scatter<<<(E1 + 255) / 256, 256, 0, stream>>>(ei1, ei1 + E1, rp1, cur1, srcs1, E1);
  // ---- CSR graph2 ----
  k_zero<<<1, 256, 0, stream>>>(cur2, N2);
  k_hist<<<(E2 + 255) / 256, 256, 0, stream>>>(ei2 + E2, cur2, E2);
  k_scan<<<1, 1024, 0, stream>>>(cur2, rp2, N2);
  k_zero<<<1, 256, 0, stream>>>(cur2, N2);
  k_scatter<<<(E2 + 255) / 256, 256, 0, stream>>>(ei2, ei2 + E2, rp2, cur2, srcs2, E2);
  // ---- GNN graph1 ----
  k_aggregate<<<(N1 + 1) / 2, 256, 0, stream>>>(x1, rp1, srcs1, bufMean, N1);
  k_sage_gemm<128><<<(N1 + 127) / 128, 256, 0, stream>>>(x1, bufMean, w1l, b1l, w1r, bufH, N1);
  k_aggregate<<<(N1 + 1) / 2, 256, 0, stream>>>(bufH, rp1, srcs1, bufMean, N1);
  k_sage_gemm<64><<<(N1 + 127) / 128, 256, 0, stream>>>(bufH, bufMean, w2l, b2l, w2r, out1b, N1);
  // ---- GNN graph2 ----
  k_aggregate<<<(N2 + 1) / 2, 256, 0, stream>>>(x2, rp2, srcs2, mean2, N2);
  k_sage_gemm<128><<<(N2 + 127) / 128, 256, 0, stream>>>(x2, mean2, w1l, b1l, w1r, h2g, N2);
  k_aggregate<<<(N2 + 1) / 2, 256, 0, stream>>>(h2g, rp2, srcs2, mean2, N2);
  k_sage_gemm<64><<<(N2 + 127) / 128, 256, 0, stream>>>(h2g, mean2, w2l, b2l, w2r, out2b, N2);
  // ---- head ----
  k_score<<<(N1 + 3) / 4, 256, 0, stream>>>(out1b, out2b, scores, N1);
  k_topk<<<Bg, 256, 0, stream>>>(scores, sel);
  k_dist_rows<<<Bg * KSEL, 256, 0, stream>>>(out1b, out2b, sel, Dm);
  k_fc1_dot<<<Bg * 128, 256, 0, stream>>>(Dm, fc1w, h1pre);
  k_fc1_ln<<<Bg, 128, 0, stream>>>(h1pre, fc1b, ln1g, ln1b, h1m);
  k_fc23<<<Bg, 64, 0, stream>>>(h1m, fc2w, fc2b, ln2g, ln2b, fc3w, fc3b, out);
}

// Round 4
// 757.494 us; speedup vs baseline: 2.3049x; 1.3380x over previous
//
#include <hip/hip_runtime.h>
#include <math.h>

#define N1 50000
#define F_IN 128
#define E1 1000000
#define Bg 10
#define NPG 5000
#define N2 199
#define E2 4000
#define KSEL 50
#define LN_EPS 1e-5f

// ---------------- CSR build ----------------
__global__ void k_zero(int* __restrict__ p, int n) {
  int i = blockIdx.x * 256 + threadIdx.x;
  if (i < n) p[i] = 0;
}

__global__ void k_hist(const int* __restrict__ dst, int* __restrict__ cnt, int E) {
  int e = blockIdx.x * 256 + threadIdx.x;
  if (e < E) atomicAdd(&cnt[dst[e]], 1);
}

// single-block exclusive scan: rp[0]=0, rp[i+1]=sum(cnt[0..i])
__global__ void k_scan(const int* __restrict__ cnt, int* __restrict__ rp, int n) {
  __shared__ int sh[1024];
  __shared__ int carry;
  int t = threadIdx.x;
  if (t == 0) { carry = 0; rp[0] = 0; }
  for (int base = 0; base < n; base += 1024) {
    __syncthreads();
    int v = (base + t < n) ? cnt[base + t] : 0;
    sh[t] = v;
    __syncthreads();
    for (int off = 1; off < 1024; off <<= 1) {
      int add = (t >= off) ? sh[t - off] : 0;
      __syncthreads();
      sh[t] += add;
      __syncthreads();
    }
    if (base + t < n) rp[base + t + 1] = carry + sh[t];
    __syncthreads();
    if (t == 0) carry += sh[1023];
  }
}

__global__ void k_scatter(const int* __restrict__ src, const int* __restrict__ dst,
                          const int* __restrict__ rp, int* __restrict__ cur,
                          int* __restrict__ srcs, int E) {
  int e = blockIdx.x * 256 + threadIdx.x;
  if (e < E) {
    int d = dst[e];
    int pos = atomicAdd(&cur[d], 1);
    srcs[rp[d] + pos] = src[e];
  }
}

// ---------------- mean aggregation, 128-wide: 1 node per wave, float2/lane ----------------
// edge loop unrolled x4 -> 4 independent 512B row gathers in flight
__global__ void k_aggr128(const float* __restrict__ x, const int* __restrict__ rp,
                          const int* __restrict__ srcs, float* __restrict__ mean, int n) {
  int lane = threadIdx.x & 63;
  int node = blockIdx.x * 4 + (threadIdx.x >> 6);
  if (node >= n) return;
  int s = rp[node], e = rp[node + 1];
  const float2* xp = (const float2*)x;
  float2 acc = make_float2(0.f, 0.f);
  int i = s;
  for (; i + 4 <= e; i += 4) {
    int s0 = srcs[i], s1 = srcs[i + 1], s2 = srcs[i + 2], s3 = srcs[i + 3];
    float2 v0 = xp[(size_t)s0 * 64 + lane];
    float2 v1 = xp[(size_t)s1 * 64 + lane];
    float2 v2 = xp[(size_t)s2 * 64 + lane];
    float2 v3 = xp[(size_t)s3 * 64 + lane];
    acc.x += (v0.x + v1.x) + (v2.x + v3.x);
    acc.y += (v0.y + v1.y) + (v2.y + v3.y);
  }
  for (; i < e; i++) {
    float2 v = xp[(size_t)srcs[i] * 64 + lane];
    acc.x += v.x;
    acc.y += v.y;
  }
  float c = (float)((e - s) > 0 ? (e - s) : 1);
  float2 o = make_float2(acc.x / c, acc.y / c);
  *(float2*)&mean[(size_t)node * 128 + lane * 2] = o;
}

// ---------------- fused layer-2 aggregate, 64-wide ----------------
// out[node,f] = relu( mean_edges(zlr[src, f]) + bias[f] + zlr[node, 64+f] )
__global__ void k_aggr_fused64(const float* __restrict__ zlr, const float* __restrict__ bias,
                               const int* __restrict__ rp, const int* __restrict__ srcs,
                               float* __restrict__ out, int n) {
  int lane = threadIdx.x & 63;
  int node = blockIdx.x * 4 + (threadIdx.x >> 6);
  if (node >= n) return;
  int s = rp[node], e = rp[node + 1];
  float acc = 0.f;
  int i = s;
  for (; i + 4 <= e; i += 4) {
    int s0 = srcs[i], s1 = srcs[i + 1], s2 = srcs[i + 2], s3 = srcs[i + 3];
    float v0 = zlr[(size_t)s0 * 128 + lane];
    float v1 = zlr[(size_t)s1 * 128 + lane];
    float v2 = zlr[(size_t)s2 * 128 + lane];
    float v3 = zlr[(size_t)s3 * 128 + lane];
    acc += (v0 + v1) + (v2 + v3);
  }
  for (; i < e; i++) acc += zlr[(size_t)srcs[i] * 128 + lane];
  float c = (float)((e - s) > 0 ? (e - s) : 1);
  float v = acc / c + bias[lane] + zlr[(size_t)node * 128 + 64 + lane];
  out[(size_t)node * 64 + lane] = v > 0.f ? v : 0.f;
}

// ---------------- SAGE layer-1 as register-tiled GEMM ----------------
// out[n,128] = relu( mean @ wl^T + bl + xin @ wr^T ), K = 128 per phase.
__global__ __launch_bounds__(256) void k_sage_gemm128(
    const float* __restrict__ xin, const float* __restrict__ mean,
    const float* __restrict__ wl, const float* __restrict__ bl,
    const float* __restrict__ wr, float* __restrict__ out, int n) {
  constexpr int O = 128, TM = 128, TK = 32;
  constexpr int SA = TM + 4;
  constexpr int SW = O + 4;
  __shared__ float s_a[TK][SA];
  __shared__ float s_w[TK][SW];
  int t = threadIdx.x;
  int tx = t & 15, ty = t >> 4;
  int m0 = blockIdx.x * TM;
  int sub = t >> 3;
  int kv = (t & 7) << 2;

  float acc[8][8];
#pragma unroll
  for (int i = 0; i < 8; i++)
#pragma unroll
    for (int j = 0; j < 8; j++) acc[i][j] = 0.f;

  for (int ph = 0; ph < 2; ph++) {
    const float* A = ph ? xin : mean;
    const float* W = ph ? wr : wl;
    for (int k0 = 0; k0 < 128; k0 += TK) {
      __syncthreads();
#pragma unroll
      for (int p = 0; p < 4; p++) {
        int node = m0 + p * 32 + sub;
        float4 v = make_float4(0.f, 0.f, 0.f, 0.f);
        if (node < n) v = *(const float4*)&A[(size_t)node * 128 + k0 + kv];
        int col = p * 32 + sub;
        s_a[kv + 0][col] = v.x;
        s_a[kv + 1][col] = v.y;
        s_a[kv + 2][col] = v.z;
        s_a[kv + 3][col] = v.w;
      }
#pragma unroll
      for (int p = 0; p < 4; p++) {
        int j = p * 32 + sub;
        float4 v = *(const float4*)&W[(size_t)j * 128 + k0 + kv];
        s_w[kv + 0][j] = v.x;
        s_w[kv + 1][j] = v.y;
        s_w[kv + 2][j] = v.z;
        s_w[kv + 3][j] = v.w;
      }
      __syncthreads();
#pragma unroll 8
      for (int kk = 0; kk < TK; kk++) {
        float4 a0 = *(const float4*)&s_a[kk][ty * 8];
        float4 a1 = *(const float4*)&s_a[kk][ty * 8 + 4];
        float av[8] = {a0.x, a0.y, a0.z, a0.w, a1.x, a1.y, a1.z, a1.w};
        float4 w0 = *(const float4*)&s_w[kk][tx * 8];
        float4 w1 = *(const float4*)&s_w[kk][tx * 8 + 4];
        float wv[8] = {w0.x, w0.y, w0.z, w0.w, w1.x, w1.y, w1.z, w1.w};
#pragma unroll
        for (int i = 0; i < 8; i++)
#pragma unroll
          for (int j = 0; j < 8; j++) acc[i][j] = fmaf(av[i], wv[j], acc[i][j]);
      }
    }
  }
  float bj[8];
#pragma unroll
  for (int j = 0; j < 8; j++) bj[j] = bl[tx * 8 + j];
#pragma unroll
  for (int i = 0; i < 8; i++) {
    int node = m0 + ty * 8 + i;
    if (node < n) {
#pragma unroll
      for (int q = 0; q < 8; q += 4) {
        float v0 = acc[i][q + 0] + bj[q + 0];
        float v1 = acc[i][q + 1] + bj[q + 1];
        float v2 = acc[i][q + 2] + bj[q + 2];
        float v3 = acc[i][q + 3] + bj[q + 3];
        float4 o;
        o.x = v0 > 0.f ? v0 : 0.f;
        o.y = v1 > 0.f ? v1 : 0.f;
        o.z = v2 > 0.f ? v2 : 0.f;
        o.w = v3 > 0.f ? v3 : 0.f;
        *(float4*)&out[(size_t)node * 128 + tx * 8 + q] = o;
      }
    }
  }
}

// ---------------- dual linear for layer 2: zlr = [A@wl^T | A@wr^T], no bias/relu ----------------
__global__ __launch_bounds__(256) void k_lin_dual(
    const float* __restrict__ A,    // [n,128]
    const float* __restrict__ wl,   // [64,128]
    const float* __restrict__ wr,   // [64,128]
    float* __restrict__ zlr,        // [n,128]
    int n) {
  constexpr int TM = 128, TK = 32;
  constexpr int SA = TM + 4;
  constexpr int SW = 128 + 4;
  __shared__ float s_a[TK][SA];
  __shared__ float s_w[TK][SW];
  int t = threadIdx.x;
  int tx = t & 15, ty = t >> 4;
  int m0 = blockIdx.x * TM;
  int sub = t >> 3;
  int kv = (t & 7) << 2;

  float acc[8][8];
#pragma unroll
  for (int i = 0; i < 8; i++)
#pragma unroll
    for (int j = 0; j < 8; j++) acc[i][j] = 0.f;

  for (int k0 = 0; k0 < 128; k0 += TK) {
    __syncthreads();
#pragma unroll
    for (int p = 0; p < 4; p++) {
      int node = m0 + p * 32 + sub;
      float4 v = make_float4(0.f, 0.f, 0.f, 0.f);
      if (node < n) v = *(const float4*)&A[(size_t)node * 128 + k0 + kv];
      int col = p * 32 + sub;
      s_a[kv + 0][col] = v.x;
      s_a[kv + 1][col] = v.y;
      s_a[kv + 2][col] = v.z;
      s_a[kv + 3][col] = v.w;
    }
#pragma unroll
    for (int p = 0; p < 4; p++) {
      int j = p * 32 + sub;
      const float* W = (j < 64) ? &wl[(size_t)j * 128] : &wr[(size_t)(j - 64) * 128];
      float4 v = *(const float4*)&W[k0 + kv];
      s_w[kv + 0][j] = v.x;
      s_w[kv + 1][j] = v.y;
      s_w[kv + 2][j] = v.z;
      s_w[kv + 3][j] = v.w;
    }
    __syncthreads();
#pragma unroll 8
    for (int kk = 0; kk < TK; kk++) {
      float4 a0 = *(const float4*)&s_a[kk][ty * 8];
      float4 a1 = *(const float4*)&s_a[kk][ty * 8 + 4];
      float av[8] = {a0.x, a0.y, a0.z, a0.w, a1.x, a1.y, a1.z, a1.w};
      float4 w0 = *(const float4*)&s_w[kk][tx * 8];
      float4 w1 = *(const float4*)&s_w[kk][tx * 8 + 4];
      float wv[8] = {w0.x, w0.y, w0.z, w0.w, w1.x, w1.y, w1.z, w1.w};
#pragma unroll
      for (int i = 0; i < 8; i++)
#pragma unroll
        for (int j = 0; j < 8; j++) acc[i][j] = fmaf(av[i], wv[j], acc[i][j]);
    }
  }
#pragma unroll
  for (int i = 0; i < 8; i++) {
    int node = m0 + ty * 8 + i;
    if (node < n) {
#pragma unroll
      for (int q = 0; q < 8; q += 4) {
        float4 o = make_float4(acc[i][q + 0], acc[i][q + 1], acc[i][q + 2], acc[i][q + 3]);
        *(float4*)&zlr[(size_t)node * 128 + tx * 8 + q] = o;
      }
    }
  }
}

// ---------------- score: dist(out1[n], out2[198]) ----------------
__global__ void k_score(const float* __restrict__ out1, const float* __restrict__ out2,
                        float* __restrict__ scores, int n) {
  int lane = threadIdx.x & 63;
  int node = blockIdx.x * 4 + (threadIdx.x >> 6);
  if (node >= n) return;
  float a = out1[(size_t)node * 64 + lane];
  float bb = out2[198 * 64 + lane];
  float a2 = a * a, b2 = bb * bb, ab = a * bb;
  for (int off = 32; off; off >>= 1) {
    a2 += __shfl_xor(a2, off);
    b2 += __shfl_xor(b2, off);
    ab += __shfl_xor(ab, off);
  }
  if (lane == 0) {
    float d2 = a2 + b2 - 2.f * ab;
    scores[node] = sqrtf(fmaxf(d2, 0.f));
  }
}

// ---------------- stable top-50 per graph (desc, ties -> smaller index) ----------------
__global__ void k_topk(const float* __restrict__ scores, int* __restrict__ sel) {
  __shared__ float s[NPG];
  __shared__ float wbv[4];
  __shared__ int wbi[4];
  int b = blockIdx.x, t = threadIdx.x;  // 256 threads
  for (int i = t; i < NPG; i += 256) s[i] = scores[b * NPG + i];
  for (int r = 0; r < KSEL; r++) {
    __syncthreads();
    float bv = -INFINITY;
    int bi = 0x7fffffff;
    for (int i = t; i < NPG; i += 256) {
      float v = s[i];
      if (v > bv || (v == bv && i < bi)) { bv = v; bi = i; }
    }
    for (int off = 32; off; off >>= 1) {
      float ov = __shfl_down(bv, off);
      int oi = __shfl_down(bi, off);
      if (ov > bv || (ov == bv && oi < bi)) { bv = ov; bi = oi; }
    }
    if ((t & 63) == 0) { wbv[t >> 6] = bv; wbi[t >> 6] = bi; }
    __syncthreads();
    if (t == 0) {
      for (int w = 1; w < 4; w++)
        if (wbv[w] > bv || (wbv[w] == bv && wbi[w] < bi)) { bv = wbv[w]; bi = wbi[w]; }
      sel[b * KSEL + r] = b * NPG + bi;
      s[bi] = -INFINITY;
    }
  }
}

// ---------------- dist rows for selected nodes: D[500][199] ----------------
__global__ void k_dist_rows(const float* __restrict__ out1, const float* __restrict__ out2,
                            const int* __restrict__ sel, float* __restrict__ D) {
  __shared__ float arow[64];
  int i = blockIdx.x;  // 0..499
  int t = threadIdx.x; // 256
  int node = sel[i];
  if (t < 64) arow[t] = out1[(size_t)node * 64 + t];
  __syncthreads();
  float a2 = 0.f;
#pragma unroll
  for (int f = 0; f < 64; f++) a2 = fmaf(arow[f], arow[f], a2);
  for (int nn = t; nn < N2; nn += 256) {
    float dot = 0.f, b2 = 0.f;
#pragma unroll 8
    for (int f = 0; f < 64; f++) {
      float bv = out2[nn * 64 + f];
      dot = fmaf(arow[f], bv, dot);
      b2 = fmaf(bv, bv, b2);
    }
    float d2 = a2 + b2 - 2.f * dot;
    D[i * N2 + nn] = sqrtf(fmaxf(d2, 0.f));
  }
}

// ---------------- fc1 dot: one block per (b, j) output scalar ----------------
__global__ void k_fc1_dot(const float* __restrict__ D, const float* __restrict__ w,
                          float* __restrict__ h1pre) {
  constexpr int M = KSEL * N2;   // 9950
  constexpr int M2 = M / 2;      // 4975 float2
  int b = blockIdx.x >> 7;       // 0..9
  int j = blockIdx.x & 127;      // 0..127
  int t = threadIdx.x;           // 256
  const float2* wp = (const float2*)(w + (size_t)j * M);
  const float2* dp = (const float2*)(D + (size_t)b * M);
  float acc = 0.f;
  for (int m = t; m < M2; m += 256) {
    float2 wv = wp[m];
    float2 dv = dp[m];
    acc = fmaf(dv.x, wv.x, acc);
    acc = fmaf(dv.y, wv.y, acc);
  }
  for (int off = 32; off; off >>= 1) acc += __shfl_xor(acc, off);
  __shared__ float ws_[4];
  int lane = t & 63, wv_ = t >> 6;
  if (lane == 0) ws_[wv_] = acc;
  __syncthreads();
  if (t == 0) h1pre[b * 128 + j] = ws_[0] + ws_[1] + ws_[2] + ws_[3];
}

// ---------------- fc1 LN + relu: [10,128] ----------------
__global__ void k_fc1_ln(const float* __restrict__ h1pre, const float* __restrict__ bias,
                         const float* __restrict__ g, const float* __restrict__ be,
                         float* __restrict__ h1out) {
  __shared__ float wsum[2];
  int b = blockIdx.x, t = threadIdx.x;  // 128 threads
  float acc = h1pre[b * 128 + t] + bias[t];
  int lane = t & 63, wv_ = t >> 6;
  float ssum = acc;
  for (int off = 32; off; off >>= 1) ssum += __shfl_xor(ssum, off);
  if (lane == 0) wsum[wv_] = ssum;
  __syncthreads();
  float mu = (wsum[0] + wsum[1]) / 128.f;
  __syncthreads();
  float d = acc - mu;
  float vv = d * d;
  for (int off = 32; off; off >>= 1) vv += __shfl_xor(vv, off);
  if (lane == 0) wsum[wv_] = vv;
  __syncthreads();
  float var = (wsum[0] + wsum[1]) / 128.f;
  float r = rsqrtf(var + LN_EPS);
  float h = d * r * g[t] + be[t];
  h1out[b * 128 + t] = h > 0.f ? h : 0.f;
}

// ---------------- fc2 + LN + relu + fc3 + sigmoid ----------------
__global__ void k_fc23(const float* __restrict__ h1, const float* __restrict__ w2,
                       const float* __restrict__ b2v, const float* __restrict__ g2,
                       const float* __restrict__ be2, const float* __restrict__ w3,
                       const float* __restrict__ b3, float* __restrict__ out) {
  int b = blockIdx.x, j = threadIdx.x;  // 64 threads = 1 wave
  __shared__ float sh1[128];
  sh1[j] = h1[b * 128 + j];
  sh1[j + 64] = h1[b * 128 + j + 64];
  __syncthreads();
  float acc = b2v[j];
#pragma unroll 8
  for (int k = 0; k < 128; k++) acc = fmaf(sh1[k], w2[j * 128 + k], acc);
  float s = acc;
  for (int off = 32; off; off >>= 1) s += __shfl_xor(s, off);
  float mu = s * (1.f / 64.f);
  float d = acc - mu;
  float vv = d * d;
  for (int off = 32; off; off >>= 1) vv += __shfl_xor(vv, off);
  float r = rsqrtf(vv * (1.f / 64.f) + LN_EPS);
  float h = d * r * g2[j] + be2[j];
  h = h > 0.f ? h : 0.f;
  float p = h * w3[j];
  for (int off = 32; off; off >>= 1) p += __shfl_xor(p, off);
  if (j == 0) out[b] = 1.f / (1.f + expf(-(p + b3[0])));
}

extern "C" void kernel_launch(void* const* d_in, const int* in_sizes, int n_in,
                              void* d_out, int out_size, void* d_ws, size_t ws_size,
                              hipStream_t stream) {
  const float* x1 = (const float*)d_in[0];
  const int* ei1 = (const int*)d_in[1];
  // d_in[2] = batch1 (unused: equal-size contiguous graphs)
  const float* x2 = (const float*)d_in[3];
  const int* ei2 = (const int*)d_in[4];
  const float* w1l = (const float*)d_in[5];
  const float* b1l = (const float*)d_in[6];
  const float* w1r = (const float*)d_in[7];
  const float* w2l = (const float*)d_in[8];
  const float* b2l = (const float*)d_in[9];
  const float* w2r = (const float*)d_in[10];
  const float* fc1w = (const float*)d_in[11];
  const float* fc1b = (const float*)d_in[12];
  const float* ln1g = (const float*)d_in[13];
  const float* ln1b = (const float*)d_in[14];
  const float* fc2w = (const float*)d_in[15];
  const float* fc2b = (const float*)d_in[16];
  const float* ln2g = (const float*)d_in[17];
  const float* ln2b = (const float*)d_in[18];
  const float* fc3w = (const float*)d_in[19];
  const float* fc3b = (const float*)d_in[20];
  float* out = (float*)d_out;

  char* p = (char*)d_ws;
  auto alloc = [&](size_t bytes) {
    char* r = p;
    p += (bytes + 255) & ~(size_t)255;
    return r;
  };
  int* rp1 = (int*)alloc((N1 + 1) * 4);
  int* cur1 = (int*)alloc(N1 * 4);
  int* srcs1 = (int*)alloc((size_t)E1 * 4);
  int* rp2 = (int*)alloc((N2 + 1) * 4);
  int* cur2 = (int*)alloc(N2 * 4);
  int* srcs2 = (int*)alloc(E2 * 4);
  float* bufMean = (float*)alloc((size_t)N1 * 128 * 4);  // also reused as zlr
  float* bufH = (float*)alloc((size_t)N1 * 128 * 4);
  float* out1b = (float*)alloc((size_t)N1 * 64 * 4);
  float* mean2 = (float*)alloc((size_t)N2 * 128 * 4);
  float* h2g = (float*)alloc((size_t)N2 * 128 * 4);
  float* out2b = (float*)alloc((size_t)N2 * 64 * 4);
  float* scores = (float*)alloc((size_t)N1 * 4);
  int* sel = (int*)alloc(Bg * KSEL * 4);
  float* Dm = (float*)alloc((size_t)Bg * KSEL * N2 * 4);
  float* h1pre = (float*)alloc(Bg * 128 * 4);
  float* h1m = (float*)alloc(Bg * 128 * 4);

  // ---- CSR graph1 ----
  k_zero<<<(N1 + 255) / 256, 256, 0, stream>>>(cur1, N1);
  k_hist<<<(E1 + 255) / 256, 256, 0, stream>>>(ei1 + E1, cur1, E1);
  k_scan<<<1, 1024, 0, stream>>>(cur1, rp1, N1);
  k_zero<<<(N1 + 255) / 256, 256, 0, stream>>>(cur1, N1);
  k_scatter<<<(E1 + 255) / 256, 256, 0, stream>>>(ei1, ei1 + E1, rp1, cur1, srcs1, E1);
  // ---- CSR graph2 ----
  k_zero<<<1, 256, 0, stream>>>(cur2, N2);
  k_hist<<<(E2 + 255) / 256, 256, 0, stream>>>(ei2 + E2, cur2, E2);
  k_scan<<<1, 1024, 0, stream>>>(cur2, rp2, N2);
  k_zero<<<1, 256, 0, stream>>>(cur2, N2);
  k_scatter<<<(E2 + 255) / 256, 256, 0, stream>>>(ei2, ei2 + E2, rp2, cur2, srcs2, E2);
  // ---- GNN graph1 ----
  k_aggr128<<<(N1 + 3) / 4, 256, 0, stream>>>(x1, rp1, srcs1, bufMean, N1);
  k_sage_gemm128<<<(N1 + 127) / 128, 256, 0, stream>>>(x1, bufMean, w1l, b1l, w1r, bufH, N1);
  k_lin_dual<<<(N1 + 127) / 128, 256, 0, stream>>>(bufH, w2l, w2r, bufMean, N1);
  k_aggr_fused64<<<(N1 + 3) / 4, 256, 0, stream>>>(bufMean, b2l, rp1, srcs1, out1b, N1);
  // ---- GNN graph2 ----
  k_aggr128<<<(N2 + 3) / 4, 256, 0, stream>>>(x2, rp2, srcs2, mean2, N2);
  k_sage_gemm128<<<(N2 + 127) / 128, 256, 0, stream>>>(x2, mean2, w1l, b1l, w1r, h2g, N2);
  k_lin_dual<<<(N2 + 127) / 128, 256, 0, stream>>>(h2g, w2l, w2r, mean2, N2);
  k_aggr_fused64<<<(N2 + 3) / 4, 256, 0, stream>>>(mean2, b2l, rp2, srcs2, out2b, N2);
  // ---- head ----
  k_score<<<(N1 + 3) / 4, 256, 0, stream>>>(out1b, out2b, scores, N1);
  k_topk<<<Bg, 256, 0, stream>>>(scores, sel);
  k_dist_rows<<<Bg * KSEL, 256, 0, stream>>>(out1b, out2b, sel, Dm);
  k_fc1_dot<<<Bg * 128, 256, 0, stream>>>(Dm, fc1w, h1pre);
  k_fc1_ln<<<Bg, 128, 0, stream>>>(h1pre, fc1b, ln1g, ln1b, h1m);
  k_fc23<<<Bg, 64, 0, stream>>>(h1m, fc2w, fc2b, ln2g, ln2b, fc3w, fc3b, out);
}

// Round 5
// 608.739 us; speedup vs baseline: 2.8681x; 1.2444x over previous
//
#include <hip/hip_runtime.h>
#include <math.h>

#define N1 50000
#define F_IN 128
#define E1 1000000
#define Bg 10
#define NPG 5000
#define N2 199
#define E2 4000
#define KSEL 50
#define LN_EPS 1e-5f
#define CHUNKS 8
#define CHSZ 625  // NPG / CHUNKS

// ---------------- CSR build ----------------
__global__ void k_zero(int* __restrict__ p, int n) {
  int i = blockIdx.x * 256 + threadIdx.x;
  if (i < n) p[i] = 0;
}

__global__ void k_hist(const int* __restrict__ dst, int* __restrict__ cnt, int E) {
  int e = blockIdx.x * 256 + threadIdx.x;
  if (e < E) atomicAdd(&cnt[dst[e]], 1);
}

// single-block exclusive scan via wave shfl-scans: rp[0]=0, rp[i+1]=sum(cnt[0..i])
__global__ void k_scan(const int* __restrict__ cnt, int* __restrict__ rp, int n) {
  __shared__ int wsums[16];
  __shared__ int carry_s;
  int t = threadIdx.x;          // 1024
  int lane = t & 63, w = t >> 6;
  if (t == 0) { carry_s = 0; rp[0] = 0; }
  __syncthreads();
  for (int base = 0; base < n; base += 1024) {
    int v = (base + t < n) ? cnt[base + t] : 0;
    int x = v;
#pragma unroll
    for (int off = 1; off < 64; off <<= 1) {
      int y = __shfl_up(x, off);
      if (lane >= off) x += y;
    }
    if (lane == 63) wsums[w] = x;
    __syncthreads();
    if (w == 0) {
      int s = (lane < 16) ? wsums[lane] : 0;
#pragma unroll
      for (int off = 1; off < 16; off <<= 1) {
        int y = __shfl_up(s, off);
        if (lane >= off) s += y;
      }
      if (lane < 16) wsums[lane] = s;  // inclusive scan of wave sums
    }
    __syncthreads();
    int prefix = carry_s + (w > 0 ? wsums[w - 1] : 0);
    if (base + t < n) rp[base + t + 1] = prefix + x;
    __syncthreads();
    if (t == 0) carry_s += wsums[15];
    __syncthreads();
  }
}

__global__ void k_scatter(const int* __restrict__ src, const int* __restrict__ dst,
                          const int* __restrict__ rp, int* __restrict__ cur,
                          int* __restrict__ srcs, int E) {
  int e = blockIdx.x * 256 + threadIdx.x;
  if (e < E) {
    int d = dst[e];
    int pos = atomicAdd(&cur[d], 1);
    srcs[rp[d] + pos] = src[e];
  }
}

// ---------------- mean aggregation, 128-wide: 1 node per wave, float2/lane ----------------
__global__ void k_aggr128(const float* __restrict__ x, const int* __restrict__ rp,
                          const int* __restrict__ srcs, float* __restrict__ mean, int n) {
  int lane = threadIdx.x & 63;
  int node = blockIdx.x * 4 + (threadIdx.x >> 6);
  if (node >= n) return;
  int s = rp[node], e = rp[node + 1];
  const float2* xp = (const float2*)x;
  float2 acc = make_float2(0.f, 0.f);
  int i = s;
  for (; i + 4 <= e; i += 4) {
    int s0 = srcs[i], s1 = srcs[i + 1], s2 = srcs[i + 2], s3 = srcs[i + 3];
    float2 v0 = xp[(size_t)s0 * 64 + lane];
    float2 v1 = xp[(size_t)s1 * 64 + lane];
    float2 v2 = xp[(size_t)s2 * 64 + lane];
    float2 v3 = xp[(size_t)s3 * 64 + lane];
    acc.x += (v0.x + v1.x) + (v2.x + v3.x);
    acc.y += (v0.y + v1.y) + (v2.y + v3.y);
  }
  for (; i < e; i++) {
    float2 v = xp[(size_t)srcs[i] * 64 + lane];
    acc.x += v.x;
    acc.y += v.y;
  }
  float c = (float)((e - s) > 0 ? (e - s) : 1);
  float2 o = make_float2(acc.x / c, acc.y / c);
  *(float2*)&mean[(size_t)node * 128 + lane * 2] = o;
}

// ---------------- fused layer-2 aggregate, 64-wide ----------------
__global__ void k_aggr_fused64(const float* __restrict__ zlr, const float* __restrict__ bias,
                               const int* __restrict__ rp, const int* __restrict__ srcs,
                               float* __restrict__ out, int n) {
  int lane = threadIdx.x & 63;
  int node = blockIdx.x * 4 + (threadIdx.x >> 6);
  if (node >= n) return;
  int s = rp[node], e = rp[node + 1];
  float acc = 0.f;
  int i = s;
  for (; i + 4 <= e; i += 4) {
    int s0 = srcs[i], s1 = srcs[i + 1], s2 = srcs[i + 2], s3 = srcs[i + 3];
    float v0 = zlr[(size_t)s0 * 128 + lane];
    float v1 = zlr[(size_t)s1 * 128 + lane];
    float v2 = zlr[(size_t)s2 * 128 + lane];
    float v3 = zlr[(size_t)s3 * 128 + lane];
    acc += (v0 + v1) + (v2 + v3);
  }
  for (; i < e; i++) acc += zlr[(size_t)srcs[i] * 128 + lane];
  float c = (float)((e - s) > 0 ? (e - s) : 1);
  float v = acc / c + bias[lane] + zlr[(size_t)node * 128 + 64 + lane];
  out[(size_t)node * 64 + lane] = v > 0.f ? v : 0.f;
}

// ---------------- SAGE layer-1 as register-tiled GEMM ----------------
__global__ __launch_bounds__(256) void k_sage_gemm128(
    const float* __restrict__ xin, const float* __restrict__ mean,
    const float* __restrict__ wl, const float* __restrict__ bl,
    const float* __restrict__ wr, float* __restrict__ out, int n) {
  constexpr int O = 128, TM = 128, TK = 32;
  constexpr int SA = TM + 4;
  constexpr int SW = O + 4;
  __shared__ float s_a[TK][SA];
  __shared__ float s_w[TK][SW];
  int t = threadIdx.x;
  int tx = t & 15, ty = t >> 4;
  int m0 = blockIdx.x * TM;
  int sub = t >> 3;
  int kv = (t & 7) << 2;

  float acc[8][8];
#pragma unroll
  for (int i = 0; i < 8; i++)
#pragma unroll
    for (int j = 0; j < 8; j++) acc[i][j] = 0.f;

  for (int ph = 0; ph < 2; ph++) {
    const float* A = ph ? xin : mean;
    const float* W = ph ? wr : wl;
    for (int k0 = 0; k0 < 128; k0 += TK) {
      __syncthreads();
#pragma unroll
      for (int p = 0; p < 4; p++) {
        int node = m0 + p * 32 + sub;
        float4 v = make_float4(0.f, 0.f, 0.f, 0.f);
        if (node < n) v = *(const float4*)&A[(size_t)node * 128 + k0 + kv];
        int col = p * 32 + sub;
        s_a[kv + 0][col] = v.x;
        s_a[kv + 1][col] = v.y;
        s_a[kv + 2][col] = v.z;
        s_a[kv + 3][col] = v.w;
      }
#pragma unroll
      for (int p = 0; p < 4; p++) {
        int j = p * 32 + sub;
        float4 v = *(const float4*)&W[(size_t)j * 128 + k0 + kv];
        s_w[kv + 0][j] = v.x;
        s_w[kv + 1][j] = v.y;
        s_w[kv + 2][j] = v.z;
        s_w[kv + 3][j] = v.w;
      }
      __syncthreads();
#pragma unroll 8
      for (int kk = 0; kk < TK; kk++) {
        float4 a0 = *(const float4*)&s_a[kk][ty * 8];
        float4 a1 = *(const float4*)&s_a[kk][ty * 8 + 4];
        float av[8] = {a0.x, a0.y, a0.z, a0.w, a1.x, a1.y, a1.z, a1.w};
        float4 w0 = *(const float4*)&s_w[kk][tx * 8];
        float4 w1 = *(const float4*)&s_w[kk][tx * 8 + 4];
        float wv[8] = {w0.x, w0.y, w0.z, w0.w, w1.x, w1.y, w1.z, w1.w};
#pragma unroll
        for (int i = 0; i < 8; i++)
#pragma unroll
          for (int j = 0; j < 8; j++) acc[i][j] = fmaf(av[i], wv[j], acc[i][j]);
      }
    }
  }
  float bj[8];
#pragma unroll
  for (int j = 0; j < 8; j++) bj[j] = bl[tx * 8 + j];
#pragma unroll
  for (int i = 0; i < 8; i++) {
    int node = m0 + ty * 8 + i;
    if (node < n) {
#pragma unroll
      for (int q = 0; q < 8; q += 4) {
        float v0 = acc[i][q + 0] + bj[q + 0];
        float v1 = acc[i][q + 1] + bj[q + 1];
        float v2 = acc[i][q + 2] + bj[q + 2];
        float v3 = acc[i][q + 3] + bj[q + 3];
        float4 o;
        o.x = v0 > 0.f ? v0 : 0.f;
        o.y = v1 > 0.f ? v1 : 0.f;
        o.z = v2 > 0.f ? v2 : 0.f;
        o.w = v3 > 0.f ? v3 : 0.f;
        *(float4*)&out[(size_t)node * 128 + tx * 8 + q] = o;
      }
    }
  }
}

// ---------------- dual linear for layer 2: zlr = [A@wl^T | A@wr^T] ----------------
__global__ __launch_bounds__(256) void k_lin_dual(
    const float* __restrict__ A, const float* __restrict__ wl,
    const float* __restrict__ wr, float* __restrict__ zlr, int n) {
  constexpr int TM = 128, TK = 32;
  constexpr int SA = TM + 4;
  constexpr int SW = 128 + 4;
  __shared__ float s_a[TK][SA];
  __shared__ float s_w[TK][SW];
  int t = threadIdx.x;
  int tx = t & 15, ty = t >> 4;
  int m0 = blockIdx.x * TM;
  int sub = t >> 3;
  int kv = (t & 7) << 2;

  float acc[8][8];
#pragma unroll
  for (int i = 0; i < 8; i++)
#pragma unroll
    for (int j = 0; j < 8; j++) acc[i][j] = 0.f;

  for (int k0 = 0; k0 < 128; k0 += TK) {
    __syncthreads();
#pragma unroll
    for (int p = 0; p < 4; p++) {
      int node = m0 + p * 32 + sub;
      float4 v = make_float4(0.f, 0.f, 0.f, 0.f);
      if (node < n) v = *(const float4*)&A[(size_t)node * 128 + k0 + kv];
      int col = p * 32 + sub;
      s_a[kv + 0][col] = v.x;
      s_a[kv + 1][col] = v.y;
      s_a[kv + 2][col] = v.z;
      s_a[kv + 3][col] = v.w;
    }
#pragma unroll
    for (int p = 0; p < 4; p++) {
      int j = p * 32 + sub;
      const float* W = (j < 64) ? &wl[(size_t)j * 128] : &wr[(size_t)(j - 64) * 128];
      float4 v = *(const float4*)&W[k0 + kv];
      s_w[kv + 0][j] = v.x;
      s_w[kv + 1][j] = v.y;
      s_w[kv + 2][j] = v.z;
      s_w[kv + 3][j] = v.w;
    }
    __syncthreads();
#pragma unroll 8
    for (int kk = 0; kk < TK; kk++) {
      float4 a0 = *(const float4*)&s_a[kk][ty * 8];
      float4 a1 = *(const float4*)&s_a[kk][ty * 8 + 4];
      float av[8] = {a0.x, a0.y, a0.z, a0.w, a1.x, a1.y, a1.z, a1.w};
      float4 w0 = *(const float4*)&s_w[kk][tx * 8];
      float4 w1 = *(const float4*)&s_w[kk][tx * 8 + 4];
      float wv[8] = {w0.x, w0.y, w0.z, w0.w, w1.x, w1.y, w1.z, w1.w};
#pragma unroll
      for (int i = 0; i < 8; i++)
#pragma unroll
        for (int j = 0; j < 8; j++) acc[i][j] = fmaf(av[i], wv[j], acc[i][j]);
    }
  }
#pragma unroll
  for (int i = 0; i < 8; i++) {
    int node = m0 + ty * 8 + i;
    if (node < n) {
#pragma unroll
      for (int q = 0; q < 8; q += 4) {
        float4 o = make_float4(acc[i][q + 0], acc[i][q + 1], acc[i][q + 2], acc[i][q + 3]);
        *(float4*)&zlr[(size_t)node * 128 + tx * 8 + q] = o;
      }
    }
  }
}

// ---------------- score: dist(out1[n], out2[198]) ----------------
__global__ void k_score(const float* __restrict__ out1, const float* __restrict__ out2,
                        float* __restrict__ scores, int n) {
  int lane = threadIdx.x & 63;
  int node = blockIdx.x * 4 + (threadIdx.x >> 6);
  if (node >= n) return;
  float a = out1[(size_t)node * 64 + lane];
  float bb = out2[198 * 64 + lane];
  float a2 = a * a, b2 = bb * bb, ab = a * bb;
  for (int off = 32; off; off >>= 1) {
    a2 += __shfl_xor(a2, off);
    b2 += __shfl_xor(b2, off);
    ab += __shfl_xor(ab, off);
  }
  if (lane == 0) {
    float d2 = a2 + b2 - 2.f * ab;
    scores[node] = sqrtf(fmaxf(d2, 0.f));
  }
}

// ---------------- top-50: stage A — per-chunk bitonic top-50 ----------------
// key = (score_bits << 32) | ~gidx : descending key order == score desc, idx asc.
__global__ void k_topk_local(const float* __restrict__ scores,
                             unsigned long long* __restrict__ cand) {
  __shared__ unsigned long long s[1024];
  int blk = blockIdx.x;  // 0..79
  int b = blk >> 3, c = blk & 7;
  int t = threadIdx.x;   // 256
  int base = c * CHSZ;
#pragma unroll
  for (int p = 0; p < 4; p++) {
    int i = p * 256 + t;
    unsigned long long key = 0ULL;
    if (i < CHSZ) {
      int gidx = base + i;
      unsigned int bits = __float_as_uint(scores[b * NPG + gidx]);
      key = ((unsigned long long)bits << 32) | (unsigned int)(~gidx);
    }
    s[i] = key;
  }
  __syncthreads();
  for (int k = 2; k <= 1024; k <<= 1) {
    for (int j = k >> 1; j > 0; j >>= 1) {
#pragma unroll
      for (int p = 0; p < 4; p++) {
        int i = p * 256 + t;
        int l = i ^ j;
        if (l > i) {
          bool up = ((i & k) != 0);  // descending overall
          unsigned long long a = s[i], bb = s[l];
          if ((a > bb) == up) { s[i] = bb; s[l] = a; }
        }
      }
      __syncthreads();
    }
  }
  if (t < KSEL) cand[(b * CHUNKS + c) * KSEL + t] = s[t];
}

// ---------------- top-50: stage B — merge 400 candidates, emit sel ----------------
__global__ void k_topk_merge(const unsigned long long* __restrict__ cand,
                             int* __restrict__ sel) {
  __shared__ unsigned long long s[512];
  int b = blockIdx.x, t = threadIdx.x;  // 256
#pragma unroll
  for (int p = 0; p < 2; p++) {
    int i = p * 256 + t;
    s[i] = (i < CHUNKS * KSEL) ? cand[b * CHUNKS * KSEL + i] : 0ULL;
  }
  __syncthreads();
  for (int k = 2; k <= 512; k <<= 1) {
    for (int j = k >> 1; j > 0; j >>= 1) {
#pragma unroll
      for (int p = 0; p < 2; p++) {
        int i = p * 256 + t;
        int l = i ^ j;
        if (l > i) {
          bool up = ((i & k) != 0);
          unsigned long long a = s[i], bb = s[l];
          if ((a > bb) == up) { s[i] = bb; s[l] = a; }
        }
      }
      __syncthreads();
    }
  }
  if (t < KSEL) {
    int gidx = (int)(~((unsigned int)s[t]));
    sel[b * KSEL + t] = b * NPG + gidx;
  }
}

// ---------------- dist rows for selected nodes: D[500][199] ----------------
__global__ void k_dist_rows(const float* __restrict__ out1, const float* __restrict__ out2,
                            const int* __restrict__ sel, float* __restrict__ D) {
  __shared__ float arow[64];
  int i = blockIdx.x;
  int t = threadIdx.x;
  int node = sel[i];
  if (t < 64) arow[t] = out1[(size_t)node * 64 + t];
  __syncthreads();
  float a2 = 0.f;
#pragma unroll
  for (int f = 0; f < 64; f++) a2 = fmaf(arow[f], arow[f], a2);
  for (int nn = t; nn < N2; nn += 256) {
    float dot = 0.f, b2 = 0.f;
#pragma unroll 8
    for (int f = 0; f < 64; f++) {
      float bv = out2[nn * 64 + f];
      dot = fmaf(arow[f], bv, dot);
      b2 = fmaf(bv, bv, b2);
    }
    float d2 = a2 + b2 - 2.f * dot;
    D[i * N2 + nn] = sqrtf(fmaxf(d2, 0.f));
  }
}

// ---------------- fc1 dot ----------------
__global__ void k_fc1_dot(const float* __restrict__ D, const float* __restrict__ w,
                          float* __restrict__ h1pre) {
  constexpr int M = KSEL * N2;
  constexpr int M2 = M / 2;
  int b = blockIdx.x >> 7;
  int j = blockIdx.x & 127;
  int t = threadIdx.x;
  const float2* wp = (const float2*)(w + (size_t)j * M);
  const float2* dp = (const float2*)(D + (size_t)b * M);
  float acc = 0.f;
  for (int m = t; m < M2; m += 256) {
    float2 wv = wp[m];
    float2 dv = dp[m];
    acc = fmaf(dv.x, wv.x, acc);
    acc = fmaf(dv.y, wv.y, acc);
  }
  for (int off = 32; off; off >>= 1) acc += __shfl_xor(acc, off);
  __shared__ float ws_[4];
  int lane = t & 63, wv_ = t >> 6;
  if (lane == 0) ws_[wv_] = acc;
  __syncthreads();
  if (t == 0) h1pre[b * 128 + j] = ws_[0] + ws_[1] + ws_[2] + ws_[3];
}

// ---------------- fc1 LN + relu ----------------
__global__ void k_fc1_ln(const float* __restrict__ h1pre, const float* __restrict__ bias,
                         const float* __restrict__ g, const float* __restrict__ be,
                         float* __restrict__ h1out) {
  __shared__ float wsum[2];
  int b = blockIdx.x, t = threadIdx.x;
  float acc = h1pre[b * 128 + t] + bias[t];
  int lane = t & 63, wv_ = t >> 6;
  float ssum = acc;
  for (int off = 32; off; off >>= 1) ssum += __shfl_xor(ssum, off);
  if (lane == 0) wsum[wv_] = ssum;
  __syncthreads();
  float mu = (wsum[0] + wsum[1]) / 128.f;
  __syncthreads();
  float d = acc - mu;
  float vv = d * d;
  for (int off = 32; off; off >>= 1) vv += __shfl_xor(vv, off);
  if (lane == 0) wsum[wv_] = vv;
  __syncthreads();
  float var = (wsum[0] + wsum[1]) / 128.f;
  float r = rsqrtf(var + LN_EPS);
  float h = d * r * g[t] + be[t];
  h1out[b * 128 + t] = h > 0.f ? h : 0.f;
}

// ---------------- fc2 + LN + relu + fc3 + sigmoid ----------------
__global__ void k_fc23(const float* __restrict__ h1, const float* __restrict__ w2,
                       const float* __restrict__ b2v, const float* __restrict__ g2,
                       const float* __restrict__ be2, const float* __restrict__ w3,
                       const float* __restrict__ b3, float* __restrict__ out) {
  int b = blockIdx.x, j = threadIdx.x;
  __shared__ float sh1[128];
  sh1[j] = h1[b * 128 + j];
  sh1[j + 64] = h1[b * 128 + j + 64];
  __syncthreads();
  float acc = b2v[j];
#pragma unroll 8
  for (int k = 0; k < 128; k++) acc = fmaf(sh1[k], w2[j * 128 + k], acc);
  float s = acc;
  for (int off = 32; off; off >>= 1) s += __shfl_xor(s, off);
  float mu = s * (1.f / 64.f);
  float d = acc - mu;
  float vv = d * d;
  for (int off = 32; off; off >>= 1) vv += __shfl_xor(vv, off);
  float r = rsqrtf(vv * (1.f / 64.f) + LN_EPS);
  float h = d * r * g2[j] + be2[j];
  h = h > 0.f ? h : 0.f;
  float p = h * w3[j];
  for (int off = 32; off; off >>= 1) p += __shfl_xor(p, off);
  if (j == 0) out[b] = 1.f / (1.f + expf(-(p + b3[0])));
}

extern "C" void kernel_launch(void* const* d_in, const int* in_sizes, int n_in,
                              void* d_out, int out_size, void* d_ws, size_t ws_size,
                              hipStream_t stream) {
  const float* x1 = (const float*)d_in[0];
  const int* ei1 = (const int*)d_in[1];
  const float* x2 = (const float*)d_in[3];
  const int* ei2 = (const int*)d_in[4];
  const float* w1l = (const float*)d_in[5];
  const float* b1l = (const float*)d_in[6];
  const float* w1r = (const float*)d_in[7];
  const float* w2l = (const float*)d_in[8];
  const float* b2l = (const float*)d_in[9];
  const float* w2r = (const float*)d_in[10];
  const float* fc1w = (const float*)d_in[11];
  const float* fc1b = (const float*)d_in[12];
  const float* ln1g = (const float*)d_in[13];
  const float* ln1b = (const float*)d_in[14];
  const float* fc2w = (const float*)d_in[15];
  const float* fc2b = (const float*)d_in[16];
  const float* ln2g = (const float*)d_in[17];
  const float* ln2b = (const float*)d_in[18];
  const float* fc3w = (const float*)d_in[19];
  const float* fc3b = (const float*)d_in[20];
  float* out = (float*)d_out;

  char* p = (char*)d_ws;
  auto alloc = [&](size_t bytes) {
    char* r = p;
    p += (bytes + 255) & ~(size_t)255;
    return r;
  };
  int* rp1 = (int*)alloc((N1 + 1) * 4);
  int* cur1 = (int*)alloc(N1 * 4);
  int* srcs1 = (int*)alloc((size_t)E1 * 4);
  int* rp2 = (int*)alloc((N2 + 1) * 4);
  int* cur2 = (int*)alloc(N2 * 4);
  int* srcs2 = (int*)alloc(E2 * 4);
  float* bufMean = (float*)alloc((size_t)N1 * 128 * 4);  // also reused as zlr
  float* bufH = (float*)alloc((size_t)N1 * 128 * 4);
  float* out1b = (float*)alloc((size_t)N1 * 64 * 4);
  float* mean2 = (float*)alloc((size_t)N2 * 128 * 4);
  float* h2g = (float*)alloc((size_t)N2 * 128 * 4);
  float* out2b = (float*)alloc((size_t)N2 * 64 * 4);
  float* scores = (float*)alloc((size_t)N1 * 4);
  int* sel = (int*)alloc(Bg * KSEL * 4);
  unsigned long long* cand = (unsigned long long*)alloc((size_t)Bg * CHUNKS * KSEL * 8);
  float* Dm = (float*)alloc((size_t)Bg * KSEL * N2 * 4);
  float* h1pre = (float*)alloc(Bg * 128 * 4);
  float* h1m = (float*)alloc(Bg * 128 * 4);

  // ---- CSR graph1 ----
  k_zero<<<(N1 + 255) / 256, 256, 0, stream>>>(cur1, N1);
  k_hist<<<(E1 + 255) / 256, 256, 0, stream>>>(ei1 + E1, cur1, E1);
  k_scan<<<1, 1024, 0, stream>>>(cur1, rp1, N1);
  k_zero<<<(N1 + 255) / 256, 256, 0, stream>>>(cur1, N1);
  k_scatter<<<(E1 + 255) / 256, 256, 0, stream>>>(ei1, ei1 + E1, rp1, cur1, srcs1, E1);
  // ---- CSR graph2 ----
  k_zero<<<1, 256, 0, stream>>>(cur2, N2);
  k_hist<<<(E2 + 255) / 256, 256, 0, stream>>>(ei2 + E2, cur2, E2);
  k_scan<<<1, 1024, 0, stream>>>(cur2, rp2, N2);
  k_zero<<<1, 256, 0, stream>>>(cur2, N2);
  k_scatter<<<(E2 + 255) / 256, 256, 0, stream>>>(ei2, ei2 + E2, rp2, cur2, srcs2, E2);
  // ---- GNN graph1 ----
  k_aggr128<<<(N1 + 3) / 4, 256, 0, stream>>>(x1, rp1, srcs1, bufMean, N1);
  k_sage_gemm128<<<(N1 + 127) / 128, 256, 0, stream>>>(x1, bufMean, w1l, b1l, w1r, bufH, N1);
  k_lin_dual<<<(N1 + 127) / 128, 256, 0, stream>>>(bufH, w2l, w2r, bufMean, N1);
  k_aggr_fused64<<<(N1 + 3) / 4, 256, 0, stream>>>(bufMean, b2l, rp1, srcs1, out1b, N1);
  // ---- GNN graph2 ----
  k_aggr128<<<(N2 + 3) / 4, 256, 0, stream>>>(x2, rp2, srcs2, mean2, N2);
  k_sage_gemm128<<<(N2 + 127) / 128, 256, 0, stream>>>(x2, mean2, w1l, b1l, w1r, h2g, N2);
  k_lin_dual<<<(N2 + 127) / 128, 256, 0, stream>>>(h2g, w2l, w2r, mean2, N2);
  k_aggr_fused64<<<(N2 + 3) / 4, 256, 0, stream>>>(mean2, b2l, rp2, srcs2, out2b, N2);
  // ---- head ----
  k_score<<<(N1 + 3) / 4, 256, 0, stream>>>(out1b, out2b, scores, N1);
  k_topk_local<<<Bg * CHUNKS, 256, 0, stream>>>(scores, cand);
  k_topk_merge<<<Bg, 256, 0, stream>>>(cand, sel);
  k_dist_rows<<<Bg * KSEL, 256, 0, stream>>>(out1b, out2b, sel, Dm);
  k_fc1_dot<<<Bg * 128, 256, 0, stream>>>(Dm, fc1w, h1pre);
  k_fc1_ln<<<Bg, 128, 0, stream>>>(h1pre, fc1b, ln1g, ln1b, h1m);
  k_fc23<<<Bg, 64, 0, stream>>>(h1m, fc2w, fc2b, ln2g, ln2b, fc3w, fc3b, out);
}

// Round 6
// 572.293 us; speedup vs baseline: 3.0507x; 1.0637x over previous
//
#include <hip/hip_runtime.h>
#include <math.h>

#define N1 50000
#define F_IN 128
#define E1 1000000
#define Bg 10
#define NPG 5000
#define N2 199
#define E2 4000
#define KSEL 50
#define LN_EPS 1e-5f
#define CHUNKS 8
#define CHSZ 625  // NPG / CHUNKS
#define SCAN_B 49 // ceil(N1/1024)

typedef unsigned long long ull;

// ---------------- CSR build (graph1) ----------------
__global__ void k_zero(int* __restrict__ p, int n) {
  int i = blockIdx.x * 256 + threadIdx.x;
  if (i < n) p[i] = 0;
}

__global__ void k_hist(const int* __restrict__ dst, int* __restrict__ cnt, int E) {
  int e = blockIdx.x * 256 + threadIdx.x;
  if (e < E) atomicAdd(&cnt[dst[e]], 1);
}

// S1: per-block inclusive scan of cnt -> rp[i+1] (pre-offset), block totals -> bsum
__global__ void k_scan_s1(const int* __restrict__ cnt, int* __restrict__ rp,
                          int* __restrict__ bsum, int n) {
  __shared__ int wsums[16];
  int t = threadIdx.x, lane = t & 63, w = t >> 6;
  int base = blockIdx.x * 1024;
  int v = (base + t < n) ? cnt[base + t] : 0;
  int x = v;
#pragma unroll
  for (int off = 1; off < 64; off <<= 1) {
    int y = __shfl_up(x, off);
    if (lane >= off) x += y;
  }
  if (lane == 63) wsums[w] = x;
  __syncthreads();
  if (w == 0) {
    int s = (lane < 16) ? wsums[lane] : 0;
#pragma unroll
    for (int off = 1; off < 16; off <<= 1) {
      int y = __shfl_up(s, off);
      if (lane >= off) s += y;
    }
    if (lane < 16) wsums[lane] = s;
  }
  __syncthreads();
  int prefix = (w > 0 ? wsums[w - 1] : 0);
  if (base + t < n) rp[base + t + 1] = prefix + x;
  if (t == 0) bsum[blockIdx.x] = wsums[15];
}

// S2: exclusive scan of SCAN_B block sums (1 block, 64 threads)
__global__ void k_scan_s2(const int* __restrict__ bsum, int* __restrict__ boff, int nb) {
  int t = threadIdx.x;
  int v = (t < nb) ? bsum[t] : 0;
  int x = v;
#pragma unroll
  for (int off = 1; off < 64; off <<= 1) {
    int y = __shfl_up(x, off);
    if (t >= off) x += y;
  }
  if (t < nb) boff[t] = x - v;
}

// S3: add block offsets; also cur[i] = final rp[i] (scatter start positions)
__global__ void k_scan_s3(int* __restrict__ rp, const int* __restrict__ boff,
                          int* __restrict__ cur, int n) {
  int t = threadIdx.x, blk = blockIdx.x;
  int base = blk * 1024, i = base + t;
  int off = boff[blk];
  int pre = 0;
  if (i < n && t > 0) pre = rp[i];  // this block's pre-offset local prefix
  __syncthreads();
  if (i < n) {
    rp[i + 1] += off;
    cur[i] = off + pre;
  }
  if (i == 0) rp[0] = 0;
}

__global__ void k_scatter(const int* __restrict__ src, const int* __restrict__ dst,
                          int* __restrict__ cur, int* __restrict__ srcs, int E) {
  int e = blockIdx.x * 256 + threadIdx.x;
  if (e < E) {
    int d = dst[e];
    int pos = atomicAdd(&cur[d], 1);
    srcs[pos] = src[e];
  }
}

// ---------------- fused CSR build for graph2 (1 block) ----------------
__global__ void k_csr_small(const int* __restrict__ ei, int* __restrict__ rp,
                            int* __restrict__ srcs) {
  __shared__ int cnt[N2];
  __shared__ int curp[N2];
  int t = threadIdx.x;  // 256
  const int* src = ei;
  const int* dst = ei + E2;
  for (int i = t; i < N2; i += 256) cnt[i] = 0;
  __syncthreads();
  for (int e = t; e < E2; e += 256) atomicAdd(&cnt[dst[e]], 1);
  __syncthreads();
  if (t == 0) {
    int run = 0;
    rp[0] = 0;
    for (int i = 0; i < N2; i++) {
      curp[i] = run;
      run += cnt[i];
      rp[i + 1] = run;
    }
  }
  __syncthreads();
  for (int e = t; e < E2; e += 256) {
    int d = dst[e];
    int pos = atomicAdd(&curp[d], 1);
    srcs[pos] = src[e];
  }
}

// ---------------- mean aggregation, 1 node/wave, float2/lane, unroll 8 ----------------
__global__ void k_aggr128(const float* __restrict__ x, const int* __restrict__ rp,
                          const int* __restrict__ srcs, float* __restrict__ mean, int n) {
  int lane = threadIdx.x & 63;
  int node = blockIdx.x * 4 + (threadIdx.x >> 6);
  if (node >= n) return;
  int s = rp[node], e = rp[node + 1];
  const float2* xp = (const float2*)x;
  float2 acc = make_float2(0.f, 0.f);
  int i = s;
  for (; i + 8 <= e; i += 8) {
    int s0 = srcs[i], s1 = srcs[i + 1], s2 = srcs[i + 2], s3 = srcs[i + 3];
    int s4 = srcs[i + 4], s5 = srcs[i + 5], s6 = srcs[i + 6], s7 = srcs[i + 7];
    float2 v0 = xp[(size_t)s0 * 64 + lane];
    float2 v1 = xp[(size_t)s1 * 64 + lane];
    float2 v2 = xp[(size_t)s2 * 64 + lane];
    float2 v3 = xp[(size_t)s3 * 64 + lane];
    float2 v4 = xp[(size_t)s4 * 64 + lane];
    float2 v5 = xp[(size_t)s5 * 64 + lane];
    float2 v6 = xp[(size_t)s6 * 64 + lane];
    float2 v7 = xp[(size_t)s7 * 64 + lane];
    acc.x += ((v0.x + v1.x) + (v2.x + v3.x)) + ((v4.x + v5.x) + (v6.x + v7.x));
    acc.y += ((v0.y + v1.y) + (v2.y + v3.y)) + ((v4.y + v5.y) + (v6.y + v7.y));
  }
  for (; i < e; i++) {
    float2 v = xp[(size_t)srcs[i] * 64 + lane];
    acc.x += v.x;
    acc.y += v.y;
  }
  float c = (float)((e - s) > 0 ? (e - s) : 1);
  float2 o = make_float2(acc.x / c, acc.y / c);
  *(float2*)&mean[(size_t)node * 128 + lane * 2] = o;
}

// ---------------- fused layer-2 aggregate, 64-wide, unroll 8 ----------------
__global__ void k_aggr_fused64(const float* __restrict__ zlr, const float* __restrict__ bias,
                               const int* __restrict__ rp, const int* __restrict__ srcs,
                               float* __restrict__ out, int n) {
  int lane = threadIdx.x & 63;
  int node = blockIdx.x * 4 + (threadIdx.x >> 6);
  if (node >= n) return;
  int s = rp[node], e = rp[node + 1];
  float acc = 0.f;
  int i = s;
  for (; i + 8 <= e; i += 8) {
    int s0 = srcs[i], s1 = srcs[i + 1], s2 = srcs[i + 2], s3 = srcs[i + 3];
    int s4 = srcs[i + 4], s5 = srcs[i + 5], s6 = srcs[i + 6], s7 = srcs[i + 7];
    float v0 = zlr[(size_t)s0 * 128 + lane];
    float v1 = zlr[(size_t)s1 * 128 + lane];
    float v2 = zlr[(size_t)s2 * 128 + lane];
    float v3 = zlr[(size_t)s3 * 128 + lane];
    float v4 = zlr[(size_t)s4 * 128 + lane];
    float v5 = zlr[(size_t)s5 * 128 + lane];
    float v6 = zlr[(size_t)s6 * 128 + lane];
    float v7 = zlr[(size_t)s7 * 128 + lane];
    acc += ((v0 + v1) + (v2 + v3)) + ((v4 + v5) + (v6 + v7));
  }
  for (; i < e; i++) acc += zlr[(size_t)srcs[i] * 128 + lane];
  float c = (float)((e - s) > 0 ? (e - s) : 1);
  float v = acc / c + bias[lane] + zlr[(size_t)node * 128 + 64 + lane];
  out[(size_t)node * 64 + lane] = v > 0.f ? v : 0.f;
}

// ---------------- SAGE layer-1 as register-tiled GEMM ----------------
__global__ __launch_bounds__(256) void k_sage_gemm128(
    const float* __restrict__ xin, const float* __restrict__ mean,
    const float* __restrict__ wl, const float* __restrict__ bl,
    const float* __restrict__ wr, float* __restrict__ out, int n) {
  constexpr int O = 128, TM = 128, TK = 32;
  constexpr int SA = TM + 4;
  constexpr int SW = O + 4;
  __shared__ float s_a[TK][SA];
  __shared__ float s_w[TK][SW];
  int t = threadIdx.x;
  int tx = t & 15, ty = t >> 4;
  int m0 = blockIdx.x * TM;
  int sub = t >> 3;
  int kv = (t & 7) << 2;

  float acc[8][8];
#pragma unroll
  for (int i = 0; i < 8; i++)
#pragma unroll
    for (int j = 0; j < 8; j++) acc[i][j] = 0.f;

  for (int ph = 0; ph < 2; ph++) {
    const float* A = ph ? xin : mean;
    const float* W = ph ? wr : wl;
    for (int k0 = 0; k0 < 128; k0 += TK) {
      __syncthreads();
#pragma unroll
      for (int p = 0; p < 4; p++) {
        int node = m0 + p * 32 + sub;
        float4 v = make_float4(0.f, 0.f, 0.f, 0.f);
        if (node < n) v = *(const float4*)&A[(size_t)node * 128 + k0 + kv];
        int col = p * 32 + sub;
        s_a[kv + 0][col] = v.x;
        s_a[kv + 1][col] = v.y;
        s_a[kv + 2][col] = v.z;
        s_a[kv + 3][col] = v.w;
      }
#pragma unroll
      for (int p = 0; p < 4; p++) {
        int j = p * 32 + sub;
        float4 v = *(const float4*)&W[(size_t)j * 128 + k0 + kv];
        s_w[kv + 0][j] = v.x;
        s_w[kv + 1][j] = v.y;
        s_w[kv + 2][j] = v.z;
        s_w[kv + 3][j] = v.w;
      }
      __syncthreads();
#pragma unroll 8
      for (int kk = 0; kk < TK; kk++) {
        float4 a0 = *(const float4*)&s_a[kk][ty * 8];
        float4 a1 = *(const float4*)&s_a[kk][ty * 8 + 4];
        float av[8] = {a0.x, a0.y, a0.z, a0.w, a1.x, a1.y, a1.z, a1.w};
        float4 w0 = *(const float4*)&s_w[kk][tx * 8];
        float4 w1 = *(const float4*)&s_w[kk][tx * 8 + 4];
        float wv[8] = {w0.x, w0.y, w0.z, w0.w, w1.x, w1.y, w1.z, w1.w};
#pragma unroll
        for (int i = 0; i < 8; i++)
#pragma unroll
          for (int j = 0; j < 8; j++) acc[i][j] = fmaf(av[i], wv[j], acc[i][j]);
      }
    }
  }
  float bj[8];
#pragma unroll
  for (int j = 0; j < 8; j++) bj[j] = bl[tx * 8 + j];
#pragma unroll
  for (int i = 0; i < 8; i++) {
    int node = m0 + ty * 8 + i;
    if (node < n) {
#pragma unroll
      for (int q = 0; q < 8; q += 4) {
        float v0 = acc[i][q + 0] + bj[q + 0];
        float v1 = acc[i][q + 1] + bj[q + 1];
        float v2 = acc[i][q + 2] + bj[q + 2];
        float v3 = acc[i][q + 3] + bj[q + 3];
        float4 o;
        o.x = v0 > 0.f ? v0 : 0.f;
        o.y = v1 > 0.f ? v1 : 0.f;
        o.z = v2 > 0.f ? v2 : 0.f;
        o.w = v3 > 0.f ? v3 : 0.f;
        *(float4*)&out[(size_t)node * 128 + tx * 8 + q] = o;
      }
    }
  }
}

// ---------------- dual linear for layer 2: zlr = [A@wl^T | A@wr^T] ----------------
__global__ __launch_bounds__(256) void k_lin_dual(
    const float* __restrict__ A, const float* __restrict__ wl,
    const float* __restrict__ wr, float* __restrict__ zlr, int n) {
  constexpr int TM = 128, TK = 32;
  constexpr int SA = TM + 4;
  constexpr int SW = 128 + 4;
  __shared__ float s_a[TK][SA];
  __shared__ float s_w[TK][SW];
  int t = threadIdx.x;
  int tx = t & 15, ty = t >> 4;
  int m0 = blockIdx.x * TM;
  int sub = t >> 3;
  int kv = (t & 7) << 2;

  float acc[8][8];
#pragma unroll
  for (int i = 0; i < 8; i++)
#pragma unroll
    for (int j = 0; j < 8; j++) acc[i][j] = 0.f;

  for (int k0 = 0; k0 < 128; k0 += TK) {
    __syncthreads();
#pragma unroll
    for (int p = 0; p < 4; p++) {
      int node = m0 + p * 32 + sub;
      float4 v = make_float4(0.f, 0.f, 0.f, 0.f);
      if (node < n) v = *(const float4*)&A[(size_t)node * 128 + k0 + kv];
      int col = p * 32 + sub;
      s_a[kv + 0][col] = v.x;
      s_a[kv + 1][col] = v.y;
      s_a[kv + 2][col] = v.z;
      s_a[kv + 3][col] = v.w;
    }
#pragma unroll
    for (int p = 0; p < 4; p++) {
      int j = p * 32 + sub;
      const float* W = (j < 64) ? &wl[(size_t)j * 128] : &wr[(size_t)(j - 64) * 128];
      float4 v = *(const float4*)&W[k0 + kv];
      s_w[kv + 0][j] = v.x;
      s_w[kv + 1][j] = v.y;
      s_w[kv + 2][j] = v.z;
      s_w[kv + 3][j] = v.w;
    }
    __syncthreads();
#pragma unroll 8
    for (int kk = 0; kk < TK; kk++) {
      float4 a0 = *(const float4*)&s_a[kk][ty * 8];
      float4 a1 = *(const float4*)&s_a[kk][ty * 8 + 4];
      float av[8] = {a0.x, a0.y, a0.z, a0.w, a1.x, a1.y, a1.z, a1.w};
      float4 w0 = *(const float4*)&s_w[kk][tx * 8];
      float4 w1 = *(const float4*)&s_w[kk][tx * 8 + 4];
      float wv[8] = {w0.x, w0.y, w0.z, w0.w, w1.x, w1.y, w1.z, w1.w};
#pragma unroll
      for (int i = 0; i < 8; i++)
#pragma unroll
        for (int j = 0; j < 8; j++) acc[i][j] = fmaf(av[i], wv[j], acc[i][j]);
    }
  }
#pragma unroll
  for (int i = 0; i < 8; i++) {
    int node = m0 + ty * 8 + i;
    if (node < n) {
#pragma unroll
      for (int q = 0; q < 8; q += 4) {
        float4 o = make_float4(acc[i][q + 0], acc[i][q + 1], acc[i][q + 2], acc[i][q + 3]);
        *(float4*)&zlr[(size_t)node * 128 + tx * 8 + q] = o;
      }
    }
  }
}

// ---------------- fused score + per-chunk bitonic top-50 ----------------
// key = (score_bits << 32) | ~gidx : desc key == score desc, idx asc (stable).
__global__ void k_score_topk_local(const float* __restrict__ out1,
                                   const float* __restrict__ out2,
                                   ull* __restrict__ cand) {
  __shared__ ull s[1024];
  __shared__ float brow[64];
  int blk = blockIdx.x;  // 0..79
  int b = blk >> 3, c = blk & 7;
  int t = threadIdx.x;   // 256
  if (t < 64) brow[t] = out2[198 * 64 + t];
  __syncthreads();
  const float4* b4 = (const float4*)brow;
  float b2 = 0.f;
#pragma unroll
  for (int q = 0; q < 16; q++) {
    float4 w = b4[q];
    b2 = fmaf(w.x, w.x, fmaf(w.y, w.y, fmaf(w.z, w.z, fmaf(w.w, w.w, b2))));
  }
#pragma unroll
  for (int p = 0; p < 4; p++) {
    int i = p * 256 + t;
    ull key = 0ULL;
    if (i < CHSZ) {
      int gidx = c * CHSZ + i;
      const float4* ap = (const float4*)&out1[((size_t)b * NPG + gidx) * 64];
      float dot = 0.f, a2 = 0.f;
#pragma unroll
      for (int q = 0; q < 16; q++) {
        float4 a = ap[q];
        float4 w = b4[q];
        dot = fmaf(a.x, w.x, fmaf(a.y, w.y, fmaf(a.z, w.z, fmaf(a.w, w.w, dot))));
        a2 = fmaf(a.x, a.x, fmaf(a.y, a.y, fmaf(a.z, a.z, fmaf(a.w, a.w, a2))));
      }
      float d2 = a2 + b2 - 2.f * dot;
      float sc = sqrtf(fmaxf(d2, 0.f));
      key = ((ull)__float_as_uint(sc) << 32) | (unsigned int)(~gidx);
    }
    s[i] = key;
  }
  __syncthreads();
  for (int k = 2; k <= 1024; k <<= 1) {
    for (int j = k >> 1; j > 0; j >>= 1) {
#pragma unroll
      for (int p = 0; p < 4; p++) {
        int i = p * 256 + t;
        int l = i ^ j;
        if (l > i) {
          bool up = ((i & k) != 0);
          ull a = s[i], bb = s[l];
          if ((a > bb) == up) { s[i] = bb; s[l] = a; }
        }
      }
      __syncthreads();
    }
  }
  if (t < KSEL) cand[(b * CHUNKS + c) * KSEL + t] = s[t];
}

// ---------------- top-50 merge: sort 400 candidates, emit sel ----------------
__global__ void k_topk_merge(const ull* __restrict__ cand, int* __restrict__ sel) {
  __shared__ ull s[512];
  int b = blockIdx.x, t = threadIdx.x;  // 256
#pragma unroll
  for (int p = 0; p < 2; p++) {
    int i = p * 256 + t;
    s[i] = (i < CHUNKS * KSEL) ? cand[b * CHUNKS * KSEL + i] : 0ULL;
  }
  __syncthreads();
  for (int k = 2; k <= 512; k <<= 1) {
    for (int j = k >> 1; j > 0; j >>= 1) {
#pragma unroll
      for (int p = 0; p < 2; p++) {
        int i = p * 256 + t;
        int l = i ^ j;
        if (l > i) {
          bool up = ((i & k) != 0);
          ull a = s[i], bb = s[l];
          if ((a > bb) == up) { s[i] = bb; s[l] = a; }
        }
      }
      __syncthreads();
    }
  }
  if (t < KSEL) {
    int gidx = (int)(~((unsigned int)s[t]));
    sel[b * KSEL + t] = b * NPG + gidx;
  }
}

// ---------------- dist rows for selected nodes: D[500][199] ----------------
__global__ void k_dist_rows(const float* __restrict__ out1, const float* __restrict__ out2,
                            const int* __restrict__ sel, float* __restrict__ D) {
  __shared__ float arow[64];
  int i = blockIdx.x;
  int t = threadIdx.x;
  int node = sel[i];
  if (t < 64) arow[t] = out1[(size_t)node * 64 + t];
  __syncthreads();
  float a2 = 0.f;
#pragma unroll
  for (int f = 0; f < 64; f++) a2 = fmaf(arow[f], arow[f], a2);
  for (int nn = t; nn < N2; nn += 256) {
    float dot = 0.f, b2 = 0.f;
#pragma unroll 8
    for (int f = 0; f < 64; f++) {
      float bv = out2[nn * 64 + f];
      dot = fmaf(arow[f], bv, dot);
      b2 = fmaf(bv, bv, b2);
    }
    float d2 = a2 + b2 - 2.f * dot;
    D[i * N2 + nn] = sqrtf(fmaxf(d2, 0.f));
  }
}

// ---------------- fc1 dot ----------------
__global__ void k_fc1_dot(const float* __restrict__ D, const float* __restrict__ w,
                          float* __restrict__ h1pre) {
  constexpr int M = KSEL * N2;
  constexpr int M2 = M / 2;
  int b = blockIdx.x >> 7;
  int j = blockIdx.x & 127;
  int t = threadIdx.x;
  const float2* wp = (const float2*)(w + (size_t)j * M);
  const float2* dp = (const float2*)(D + (size_t)b * M);
  float acc = 0.f;
  for (int m = t; m < M2; m += 256) {
    float2 wv = wp[m];
    float2 dv = dp[m];
    acc = fmaf(dv.x, wv.x, acc);
    acc = fmaf(dv.y, wv.y, acc);
  }
  for (int off = 32; off; off >>= 1) acc += __shfl_xor(acc, off);
  __shared__ float ws_[4];
  int lane = t & 63, wv_ = t >> 6;
  if (lane == 0) ws_[wv_] = acc;
  __syncthreads();
  if (t == 0) h1pre[b * 128 + j] = ws_[0] + ws_[1] + ws_[2] + ws_[3];
}

// ---------------- fused: fc1 bias+LN+relu, fc2+LN+relu, fc3+sigmoid ----------------
__global__ void k_fc123(const float* __restrict__ h1pre, const float* __restrict__ fc1b,
                        const float* __restrict__ g1, const float* __restrict__ be1,
                        const float* __restrict__ w2, const float* __restrict__ b2v,
                        const float* __restrict__ g2, const float* __restrict__ be2,
                        const float* __restrict__ w3, const float* __restrict__ b3,
                        float* __restrict__ out) {
  __shared__ float wsum[2];
  __shared__ float sh[128];
  int b = blockIdx.x, t = threadIdx.x;  // 128 threads
  float acc = h1pre[b * 128 + t] + fc1b[t];
  int lane = t & 63, wv_ = t >> 6;
  float ssum = acc;
  for (int off = 32; off; off >>= 1) ssum += __shfl_xor(ssum, off);
  if (lane == 0) wsum[wv_] = ssum;
  __syncthreads();
  float mu = (wsum[0] + wsum[1]) / 128.f;
  __syncthreads();
  float d = acc - mu;
  float vv = d * d;
  for (int off = 32; off; off >>= 1) vv += __shfl_xor(vv, off);
  if (lane == 0) wsum[wv_] = vv;
  __syncthreads();
  float var = (wsum[0] + wsum[1]) / 128.f;
  float r = rsqrtf(var + LN_EPS);
  float h = d * r * g1[t] + be1[t];
  sh[t] = h > 0.f ? h : 0.f;
  __syncthreads();
  if (t < 64) {
    float a2 = b2v[t];
#pragma unroll 8
    for (int k = 0; k < 128; k++) a2 = fmaf(sh[k], w2[t * 128 + k], a2);
    float s2 = a2;
    for (int off = 32; off; off >>= 1) s2 += __shfl_xor(s2, off);
    float mu2 = s2 * (1.f / 64.f);
    float d2 = a2 - mu2;
    float vv2 = d2 * d2;
    for (int off = 32; off; off >>= 1) vv2 += __shfl_xor(vv2, off);
    float r2 = rsqrtf(vv2 * (1.f / 64.f) + LN_EPS);
    float h2 = d2 * r2 * g2[t] + be2[t];
    h2 = h2 > 0.f ? h2 : 0.f;
    float pp = h2 * w3[t];
    for (int off = 32; off; off >>= 1) pp += __shfl_xor(pp, off);
    if (t == 0) out[b] = 1.f / (1.f + expf(-(pp + b3[0])));
  }
}

extern "C" void kernel_launch(void* const* d_in, const int* in_sizes, int n_in,
                              void* d_out, int out_size, void* d_ws, size_t ws_size,
                              hipStream_t stream) {
  const float* x1 = (const float*)d_in[0];
  const int* ei1 = (const int*)d_in[1];
  const float* x2 = (const float*)d_in[3];
  const int* ei2 = (const int*)d_in[4];
  const float* w1l = (const float*)d_in[5];
  const float* b1l = (const float*)d_in[6];
  const float* w1r = (const float*)d_in[7];
  const float* w2l = (const float*)d_in[8];
  const float* b2l = (const float*)d_in[9];
  const float* w2r = (const float*)d_in[10];
  const float* fc1w = (const float*)d_in[11];
  const float* fc1b = (const float*)d_in[12];
  const float* ln1g = (const float*)d_in[13];
  const float* ln1b = (const float*)d_in[14];
  const float* fc2w = (const float*)d_in[15];
  const float* fc2b = (const float*)d_in[16];
  const float* ln2g = (const float*)d_in[17];
  const float* ln2b = (const float*)d_in[18];
  const float* fc3w = (const float*)d_in[19];
  const float* fc3b = (const float*)d_in[20];
  float* out = (float*)d_out;

  char* p = (char*)d_ws;
  auto alloc = [&](size_t bytes) {
    char* r = p;
    p += (bytes + 255) & ~(size_t)255;
    return r;
  };
  int* rp1 = (int*)alloc((N1 + 1) * 4);
  int* cur1 = (int*)alloc(N1 * 4);     // cnt, then scatter cursor
  int* bsum = (int*)alloc(64 * 4);
  int* boff = (int*)alloc(64 * 4);
  int* srcs1 = (int*)alloc((size_t)E1 * 4);
  int* rp2 = (int*)alloc((N2 + 1) * 4);
  int* srcs2 = (int*)alloc(E2 * 4);
  float* bufMean = (float*)alloc((size_t)N1 * 128 * 4);  // also reused as zlr
  float* bufH = (float*)alloc((size_t)N1 * 128 * 4);
  float* out1b = (float*)alloc((size_t)N1 * 64 * 4);
  float* mean2 = (float*)alloc((size_t)N2 * 128 * 4);
  float* h2g = (float*)alloc((size_t)N2 * 128 * 4);
  float* out2b = (float*)alloc((size_t)N2 * 64 * 4);
  int* sel = (int*)alloc(Bg * KSEL * 4);
  ull* cand = (ull*)alloc((size_t)Bg * CHUNKS * KSEL * 8);
  float* Dm = (float*)alloc((size_t)Bg * KSEL * N2 * 4);
  float* h1pre = (float*)alloc(Bg * 128 * 4);

  // ---- CSR graph1 (hierarchical scan) ----
  k_zero<<<(N1 + 255) / 256, 256, 0, stream>>>(cur1, N1);
  k_hist<<<(E1 + 255) / 256, 256, 0, stream>>>(ei1 + E1, cur1, E1);
  k_scan_s1<<<SCAN_B, 1024, 0, stream>>>(cur1, rp1, bsum, N1);
  k_scan_s2<<<1, 64, 0, stream>>>(bsum, boff, SCAN_B);
  k_scan_s3<<<SCAN_B, 1024, 0, stream>>>(rp1, boff, cur1, N1);
  k_scatter<<<(E1 + 255) / 256, 256, 0, stream>>>(ei1, ei1 + E1, cur1, srcs1, E1);
  // ---- CSR graph2 (single block) ----
  k_csr_small<<<1, 256, 0, stream>>>(ei2, rp2, srcs2);
  // ---- GNN graph1 ----
  k_aggr128<<<(N1 + 3) / 4, 256, 0, stream>>>(x1, rp1, srcs1, bufMean, N1);
  k_sage_gemm128<<<(N1 + 127) / 128, 256, 0, stream>>>(x1, bufMean, w1l, b1l, w1r, bufH, N1);
  k_lin_dual<<<(N1 + 127) / 128, 256, 0, stream>>>(bufH, w2l, w2r, bufMean, N1);
  k_aggr_fused64<<<(N1 + 3) / 4, 256, 0, stream>>>(bufMean, b2l, rp1, srcs1, out1b, N1);
  // ---- GNN graph2 ----
  k_aggr128<<<(N2 + 3) / 4, 256, 0, stream>>>(x2, rp2, srcs2, mean2, N2);
  k_sage_gemm128<<<(N2 + 127) / 128, 256, 0, stream>>>(x2, mean2, w1l, b1l, w1r, h2g, N2);
  k_lin_dual<<<(N2 + 127) / 128, 256, 0, stream>>>(h2g, w2l, w2r, mean2, N2);
  k_aggr_fused64<<<(N2 + 3) / 4, 256, 0, stream>>>(mean2, b2l, rp2, srcs2, out2b, N2);
  // ---- head ----
  k_score_topk_local<<<Bg * CHUNKS, 256, 0, stream>>>(out1b, out2b, cand);
  k_topk_merge<<<Bg, 256, 0, stream>>>(cand, sel);
  k_dist_rows<<<Bg * KSEL, 256, 0, stream>>>(out1b, out2b, sel, Dm);
  k_fc1_dot<<<Bg * 128, 256, 0, stream>>>(Dm, fc1w, h1pre);
  k_fc123<<<Bg, 128, 0, stream>>>(h1pre, fc1b, ln1g, ln1b, fc2w, fc2b, ln2g, ln2b,
                                  fc3w, fc3b, out);
}

// Round 7
// 414.980 us; speedup vs baseline: 4.2072x; 1.3791x over previous
//
#include <hip/hip_runtime.h>
#include <math.h>

#define N1 50000
#define F_IN 128
#define E1 1000000
#define Bg 10
#define NPG 5000
#define N2 199
#define E2 4000
#define KSEL 50
#define LN_EPS 1e-5f
#define CHUNKS 8
#define CHSZ 625   // NPG / CHUNKS
#define EBT 8192   // edges per bucket-pass block
#define NB 49      // ceil(N1/1024) buckets
#define BCAP 24576 // per-bucket capacity (mean ~20.4k, +3sigma margin)

typedef unsigned long long ull;

// ---------------- phase B1: bin edges into 49 dst-buckets (+ graph2 CSR) ----------------
// payload: (dst & 1023) << 16 | src   (src < 50000 < 2^16)
__global__ void k_bucket(const int* __restrict__ ei1, int* __restrict__ bcnt,
                         unsigned int* __restrict__ bed,
                         const int* __restrict__ ei2, int* __restrict__ rp2,
                         int* __restrict__ srcs2) {
  int t = threadIdx.x;  // 256
  int blk = blockIdx.x;
  const int nEdgeBlocks = (E1 + EBT - 1) / EBT;
  if (blk == nEdgeBlocks) {
    // ---- graph2 CSR in one block ----
    __shared__ int cnt2[N2];
    __shared__ int cur2[N2];
    const int* src = ei2;
    const int* dst = ei2 + E2;
    for (int i = t; i < N2; i += 256) cnt2[i] = 0;
    __syncthreads();
    for (int e = t; e < E2; e += 256) atomicAdd(&cnt2[dst[e]], 1);
    __syncthreads();
    if (t == 0) {
      int run = 0;
      rp2[0] = 0;
      for (int i = 0; i < N2; i++) {
        cur2[i] = run;
        run += cnt2[i];
        rp2[i + 1] = run;
      }
    }
    __syncthreads();
    for (int e = t; e < E2; e += 256) {
      int d = dst[e];
      int pos = atomicAdd(&cur2[d], 1);
      srcs2[pos] = src[e];
    }
    return;
  }
  __shared__ int hcnt[NB];
  const int* src = ei1;
  const int* dst = ei1 + E1;
  int e0 = blk * EBT;
  int e1 = min(e0 + EBT, E1);
  if (t < NB) hcnt[t] = 0;
  __syncthreads();
  for (int e = e0 + t; e < e1; e += 256) atomicAdd(&hcnt[dst[e] >> 10], 1);
  __syncthreads();
  // reserve global range per bucket; hcnt becomes a global-position cursor
  if (t < NB) hcnt[t] = atomicAdd(&bcnt[t], hcnt[t]);
  __syncthreads();
  for (int e = e0 + t; e < e1; e += 256) {
    int d = dst[e];
    int s = src[e];
    int b = d >> 10;
    int pos = atomicAdd(&hcnt[b], 1);
    if (pos < BCAP)
      bed[(size_t)b * BCAP + pos] = ((unsigned int)(d & 1023) << 16) | (unsigned int)s;
  }
}

// ---------------- phase B2: per-bucket CSR finalize (rp + srcs), LDS-windowed ----------------
__global__ __launch_bounds__(1024) void k_csr_bucket(
    const int* __restrict__ bcnt, const unsigned int* __restrict__ bed,
    int* __restrict__ rp, int* __restrict__ srcs) {
  __shared__ int cnt[1024];
  __shared__ int cur[1024];
  __shared__ int wsums[16];
  __shared__ int s_bbase;
  int b = blockIdx.x, t = threadIdx.x;
  int lane = t & 63, w = t >> 6;
  int total = bcnt[b];
  if (total > BCAP) total = BCAP;
  cnt[t] = 0;
  if (w == 0) {  // bucket base = sum of previous buckets' counts
    int vb = (lane < b) ? min(bcnt[lane], BCAP) : 0;
    for (int off = 32; off; off >>= 1) vb += __shfl_xor(vb, off);
    if (lane == 0) s_bbase = vb;
  }
  __syncthreads();
  const unsigned int* list = bed + (size_t)b * BCAP;
  for (int e = t; e < total; e += 1024) atomicAdd(&cnt[list[e] >> 16], 1);
  __syncthreads();
  // inclusive scan of cnt[1024]
  int v = cnt[t];
  int x = v;
#pragma unroll
  for (int off = 1; off < 64; off <<= 1) {
    int y = __shfl_up(x, off);
    if (lane >= off) x += y;
  }
  if (lane == 63) wsums[w] = x;
  __syncthreads();
  if (w == 0) {
    int s = (lane < 16) ? wsums[lane] : 0;
#pragma unroll
    for (int off = 1; off < 16; off <<= 1) {
      int y = __shfl_up(s, off);
      if (lane >= off) s += y;
    }
    if (lane < 16) wsums[lane] = s;
  }
  __syncthreads();
  int incl = x + (w > 0 ? wsums[w - 1] : 0);
  int bbase = s_bbase;
  int node = b * 1024 + t;
  if (node < N1) rp[node + 1] = bbase + incl;
  cur[t] = bbase + incl - v;  // exclusive start = scatter cursor
  if (b == 0 && t == 0) rp[0] = 0;
  __syncthreads();
  for (int e = t; e < total; e += 1024) {
    unsigned int pe = list[e];
    int dl = pe >> 16;
    int pos = atomicAdd(&cur[dl], 1);
    srcs[pos] = (int)(pe & 0xFFFFu);
  }
}

// ---------------- mean aggregation, 1 node/wave, float2/lane, unroll 8; both graphs ----------------
__global__ void k_aggr128(const float* __restrict__ xA, const int* __restrict__ rpA,
                          const int* __restrict__ srcsA, float* __restrict__ meanA, int nA,
                          const float* __restrict__ xB, const int* __restrict__ rpB,
                          const int* __restrict__ srcsB, float* __restrict__ meanB, int nB,
                          int blocksA) {
  int blk = blockIdx.x;
  const float* x;
  const int* rp;
  const int* srcs;
  float* mean;
  int n, nb0;
  if (blk < blocksA) { x = xA; rp = rpA; srcs = srcsA; mean = meanA; n = nA; nb0 = blk * 4; }
  else { x = xB; rp = rpB; srcs = srcsB; mean = meanB; n = nB; nb0 = (blk - blocksA) * 4; }
  int lane = threadIdx.x & 63;
  int node = nb0 + (threadIdx.x >> 6);
  if (node >= n) return;
  int s = rp[node], e = rp[node + 1];
  const float2* xp = (const float2*)x;
  float2 acc = make_float2(0.f, 0.f);
  int i = s;
  for (; i + 8 <= e; i += 8) {
    int s0 = srcs[i], s1 = srcs[i + 1], s2 = srcs[i + 2], s3 = srcs[i + 3];
    int s4 = srcs[i + 4], s5 = srcs[i + 5], s6 = srcs[i + 6], s7 = srcs[i + 7];
    float2 v0 = xp[(size_t)s0 * 64 + lane];
    float2 v1 = xp[(size_t)s1 * 64 + lane];
    float2 v2 = xp[(size_t)s2 * 64 + lane];
    float2 v3 = xp[(size_t)s3 * 64 + lane];
    float2 v4 = xp[(size_t)s4 * 64 + lane];
    float2 v5 = xp[(size_t)s5 * 64 + lane];
    float2 v6 = xp[(size_t)s6 * 64 + lane];
    float2 v7 = xp[(size_t)s7 * 64 + lane];
    acc.x += ((v0.x + v1.x) + (v2.x + v3.x)) + ((v4.x + v5.x) + (v6.x + v7.x));
    acc.y += ((v0.y + v1.y) + (v2.y + v3.y)) + ((v4.y + v5.y) + (v6.y + v7.y));
  }
  for (; i < e; i++) {
    float2 v = xp[(size_t)srcs[i] * 64 + lane];
    acc.x += v.x;
    acc.y += v.y;
  }
  float c = (float)((e - s) > 0 ? (e - s) : 1);
  float2 o = make_float2(acc.x / c, acc.y / c);
  *(float2*)&mean[(size_t)node * 128 + lane * 2] = o;
}

// ---------------- fused layer-2 aggregate, 64-wide, unroll 8; both graphs ----------------
__global__ void k_aggr_fused64(const float* __restrict__ zA, const int* __restrict__ rpA,
                               const int* __restrict__ srcsA, float* __restrict__ outA, int nA,
                               const float* __restrict__ zB, const int* __restrict__ rpB,
                               const int* __restrict__ srcsB, float* __restrict__ outB, int nB,
                               const float* __restrict__ bias, int blocksA) {
  int blk = blockIdx.x;
  const float* zlr;
  const int* rp;
  const int* srcs;
  float* out;
  int n, nb0;
  if (blk < blocksA) { zlr = zA; rp = rpA; srcs = srcsA; out = outA; n = nA; nb0 = blk * 4; }
  else { zlr = zB; rp = rpB; srcs = srcsB; out = outB; n = nB; nb0 = (blk - blocksA) * 4; }
  int lane = threadIdx.x & 63;
  int node = nb0 + (threadIdx.x >> 6);
  if (node >= n) return;
  int s = rp[node], e = rp[node + 1];
  float acc = 0.f;
  int i = s;
  for (; i + 8 <= e; i += 8) {
    int s0 = srcs[i], s1 = srcs[i + 1], s2 = srcs[i + 2], s3 = srcs[i + 3];
    int s4 = srcs[i + 4], s5 = srcs[i + 5], s6 = srcs[i + 6], s7 = srcs[i + 7];
    float v0 = zlr[(size_t)s0 * 128 + lane];
    float v1 = zlr[(size_t)s1 * 128 + lane];
    float v2 = zlr[(size_t)s2 * 128 + lane];
    float v3 = zlr[(size_t)s3 * 128 + lane];
    float v4 = zlr[(size_t)s4 * 128 + lane];
    float v5 = zlr[(size_t)s5 * 128 + lane];
    float v6 = zlr[(size_t)s6 * 128 + lane];
    float v7 = zlr[(size_t)s7 * 128 + lane];
    acc += ((v0 + v1) + (v2 + v3)) + ((v4 + v5) + (v6 + v7));
  }
  for (; i < e; i++) acc += zlr[(size_t)srcs[i] * 128 + lane];
  float c = (float)((e - s) > 0 ? (e - s) : 1);
  float v = acc / c + bias[lane] + zlr[(size_t)node * 128 + 64 + lane];
  out[(size_t)node * 64 + lane] = v > 0.f ? v : 0.f;
}

// ---------------- SAGE layer-1 GEMM; both graphs ----------------
__global__ __launch_bounds__(256) void k_sage_gemm128(
    const float* __restrict__ xinA, const float* __restrict__ meanA,
    float* __restrict__ outA, int nA,
    const float* __restrict__ xinB, const float* __restrict__ meanB,
    float* __restrict__ outB, int nB,
    const float* __restrict__ wl, const float* __restrict__ bl,
    const float* __restrict__ wr, int blocksA) {
  constexpr int TM = 128, TK = 32;
  constexpr int SA = TM + 4;
  constexpr int SW = 128 + 4;
  __shared__ float s_a[TK][SA];
  __shared__ float s_w[TK][SW];
  int blk = blockIdx.x;
  const float* xin;
  const float* mean;
  float* out;
  int n, m0;
  if (blk < blocksA) { xin = xinA; mean = meanA; out = outA; n = nA; m0 = blk * TM; }
  else { xin = xinB; mean = meanB; out = outB; n = nB; m0 = (blk - blocksA) * TM; }
  int t = threadIdx.x;
  int tx = t & 15, ty = t >> 4;
  int sub = t >> 3;
  int kv = (t & 7) << 2;

  float acc[8][8];
#pragma unroll
  for (int i = 0; i < 8; i++)
#pragma unroll
    for (int j = 0; j < 8; j++) acc[i][j] = 0.f;

  for (int ph = 0; ph < 2; ph++) {
    const float* A = ph ? xin : mean;
    const float* W = ph ? wr : wl;
    for (int k0 = 0; k0 < 128; k0 += TK) {
      __syncthreads();
#pragma unroll
      for (int p = 0; p < 4; p++) {
        int node = m0 + p * 32 + sub;
        float4 v = make_float4(0.f, 0.f, 0.f, 0.f);
        if (node < n) v = *(const float4*)&A[(size_t)node * 128 + k0 + kv];
        int col = p * 32 + sub;
        s_a[kv + 0][col] = v.x;
        s_a[kv + 1][col] = v.y;
        s_a[kv + 2][col] = v.z;
        s_a[kv + 3][col] = v.w;
      }
#pragma unroll
      for (int p = 0; p < 4; p++) {
        int j = p * 32 + sub;
        float4 v = *(const float4*)&W[(size_t)j * 128 + k0 + kv];
        s_w[kv + 0][j] = v.x;
        s_w[kv + 1][j] = v.y;
        s_w[kv + 2][j] = v.z;
        s_w[kv + 3][j] = v.w;
      }
      __syncthreads();
#pragma unroll 8
      for (int kk = 0; kk < TK; kk++) {
        float4 a0 = *(const float4*)&s_a[kk][ty * 8];
        float4 a1 = *(const float4*)&s_a[kk][ty * 8 + 4];
        float av[8] = {a0.x, a0.y, a0.z, a0.w, a1.x, a1.y, a1.z, a1.w};
        float4 w0 = *(const float4*)&s_w[kk][tx * 8];
        float4 w1 = *(const float4*)&s_w[kk][tx * 8 + 4];
        float wv[8] = {w0.x, w0.y, w0.z, w0.w, w1.x, w1.y, w1.z, w1.w};
#pragma unroll
        for (int i = 0; i < 8; i++)
#pragma unroll
          for (int j = 0; j < 8; j++) acc[i][j] = fmaf(av[i], wv[j], acc[i][j]);
      }
    }
  }
  float bj[8];
#pragma unroll
  for (int j = 0; j < 8; j++) bj[j] = bl[tx * 8 + j];
#pragma unroll
  for (int i = 0; i < 8; i++) {
    int node = m0 + ty * 8 + i;
    if (node < n) {
#pragma unroll
      for (int q = 0; q < 8; q += 4) {
        float v0 = acc[i][q + 0] + bj[q + 0];
        float v1 = acc[i][q + 1] + bj[q + 1];
        float v2 = acc[i][q + 2] + bj[q + 2];
        float v3 = acc[i][q + 3] + bj[q + 3];
        float4 o;
        o.x = v0 > 0.f ? v0 : 0.f;
        o.y = v1 > 0.f ? v1 : 0.f;
        o.z = v2 > 0.f ? v2 : 0.f;
        o.w = v3 > 0.f ? v3 : 0.f;
        *(float4*)&out[(size_t)node * 128 + tx * 8 + q] = o;
      }
    }
  }
}

// ---------------- dual linear layer 2: zlr = [A@wl^T | A@wr^T]; both graphs ----------------
__global__ __launch_bounds__(256) void k_lin_dual(
    const float* __restrict__ AA, float* __restrict__ zA, int nA,
    const float* __restrict__ AB, float* __restrict__ zB, int nB,
    const float* __restrict__ wl, const float* __restrict__ wr, int blocksA) {
  constexpr int TM = 128, TK = 32;
  constexpr int SA = TM + 4;
  constexpr int SW = 128 + 4;
  __shared__ float s_a[TK][SA];
  __shared__ float s_w[TK][SW];
  int blk = blockIdx.x;
  const float* A;
  float* zlr;
  int n, m0;
  if (blk < blocksA) { A = AA; zlr = zA; n = nA; m0 = blk * TM; }
  else { A = AB; zlr = zB; n = nB; m0 = (blk - blocksA) * TM; }
  int t = threadIdx.x;
  int tx = t & 15, ty = t >> 4;
  int sub = t >> 3;
  int kv = (t & 7) << 2;

  float acc[8][8];
#pragma unroll
  for (int i = 0; i < 8; i++)
#pragma unroll
    for (int j = 0; j < 8; j++) acc[i][j] = 0.f;

  for (int k0 = 0; k0 < 128; k0 += TK) {
    __syncthreads();
#pragma unroll
    for (int p = 0; p < 4; p++) {
      int node = m0 + p * 32 + sub;
      float4 v = make_float4(0.f, 0.f, 0.f, 0.f);
      if (node < n) v = *(const float4*)&A[(size_t)node * 128 + k0 + kv];
      int col = p * 32 + sub;
      s_a[kv + 0][col] = v.x;
      s_a[kv + 1][col] = v.y;
      s_a[kv + 2][col] = v.z;
      s_a[kv + 3][col] = v.w;
    }
#pragma unroll
    for (int p = 0; p < 4; p++) {
      int j = p * 32 + sub;
      const float* W = (j < 64) ? &wl[(size_t)j * 128] : &wr[(size_t)(j - 64) * 128];
      float4 v = *(const float4*)&W[k0 + kv];
      s_w[kv + 0][j] = v.x;
      s_w[kv + 1][j] = v.y;
      s_w[kv + 2][j] = v.z;
      s_w[kv + 3][j] = v.w;
    }
    __syncthreads();
#pragma unroll 8
    for (int kk = 0; kk < TK; kk++) {
      float4 a0 = *(const float4*)&s_a[kk][ty * 8];
      float4 a1 = *(const float4*)&s_a[kk][ty * 8 + 4];
      float av[8] = {a0.x, a0.y, a0.z, a0.w, a1.x, a1.y, a1.z, a1.w};
      float4 w0 = *(const float4*)&s_w[kk][tx * 8];
      float4 w1 = *(const float4*)&s_w[kk][tx * 8 + 4];
      float wv[8] = {w0.x, w0.y, w0.z, w0.w, w1.x, w1.y, w1.z, w1.w};
#pragma unroll
      for (int i = 0; i < 8; i++)
#pragma unroll
        for (int j = 0; j < 8; j++) acc[i][j] = fmaf(av[i], wv[j], acc[i][j]);
    }
  }
#pragma unroll
  for (int i = 0; i < 8; i++) {
    int node = m0 + ty * 8 + i;
    if (node < n) {
#pragma unroll
      for (int q = 0; q < 8; q += 4) {
        float4 o = make_float4(acc[i][q + 0], acc[i][q + 1], acc[i][q + 2], acc[i][q + 3]);
        *(float4*)&zlr[(size_t)node * 128 + tx * 8 + q] = o;
      }
    }
  }
}

// ---------------- fused score + per-chunk bitonic top-50 ----------------
__global__ void k_score_topk_local(const float* __restrict__ out1,
                                   const float* __restrict__ out2,
                                   ull* __restrict__ cand) {
  __shared__ ull s[1024];
  __shared__ float brow[64];
  int blk = blockIdx.x;
  int b = blk >> 3, c = blk & 7;
  int t = threadIdx.x;
  if (t < 64) brow[t] = out2[198 * 64 + t];
  __syncthreads();
  const float4* b4 = (const float4*)brow;
  float b2 = 0.f;
#pragma unroll
  for (int q = 0; q < 16; q++) {
    float4 w = b4[q];
    b2 = fmaf(w.x, w.x, fmaf(w.y, w.y, fmaf(w.z, w.z, fmaf(w.w, w.w, b2))));
  }
#pragma unroll
  for (int p = 0; p < 4; p++) {
    int i = p * 256 + t;
    ull key = 0ULL;
    if (i < CHSZ) {
      int gidx = c * CHSZ + i;
      const float4* ap = (const float4*)&out1[((size_t)b * NPG + gidx) * 64];
      float dot = 0.f, a2 = 0.f;
#pragma unroll
      for (int q = 0; q < 16; q++) {
        float4 a = ap[q];
        float4 w = b4[q];
        dot = fmaf(a.x, w.x, fmaf(a.y, w.y, fmaf(a.z, w.z, fmaf(a.w, w.w, dot))));
        a2 = fmaf(a.x, a.x, fmaf(a.y, a.y, fmaf(a.z, a.z, fmaf(a.w, a.w, a2))));
      }
      float d2 = a2 + b2 - 2.f * dot;
      float sc = sqrtf(fmaxf(d2, 0.f));
      key = ((ull)__float_as_uint(sc) << 32) | (unsigned int)(~gidx);
    }
    s[i] = key;
  }
  __syncthreads();
  for (int k = 2; k <= 1024; k <<= 1) {
    for (int j = k >> 1; j > 0; j >>= 1) {
#pragma unroll
      for (int p = 0; p < 4; p++) {
        int i = p * 256 + t;
        int l = i ^ j;
        if (l > i) {
          bool up = ((i & k) != 0);
          ull a = s[i], bb = s[l];
          if ((a > bb) == up) { s[i] = bb; s[l] = a; }
        }
      }
      __syncthreads();
    }
  }
  if (t < KSEL) cand[(b * CHUNKS + c) * KSEL + t] = s[t];
}

// ---------------- top-50 merge ----------------
__global__ void k_topk_merge(const ull* __restrict__ cand, int* __restrict__ sel) {
  __shared__ ull s[512];
  int b = blockIdx.x, t = threadIdx.x;
#pragma unroll
  for (int p = 0; p < 2; p++) {
    int i = p * 256 + t;
    s[i] = (i < CHUNKS * KSEL) ? cand[b * CHUNKS * KSEL + i] : 0ULL;
  }
  __syncthreads();
  for (int k = 2; k <= 512; k <<= 1) {
    for (int j = k >> 1; j > 0; j >>= 1) {
#pragma unroll
      for (int p = 0; p < 2; p++) {
        int i = p * 256 + t;
        int l = i ^ j;
        if (l > i) {
          bool up = ((i & k) != 0);
          ull a = s[i], bb = s[l];
          if ((a > bb) == up) { s[i] = bb; s[l] = a; }
        }
      }
      __syncthreads();
    }
  }
  if (t < KSEL) {
    int gidx = (int)(~((unsigned int)s[t]));
    sel[b * KSEL + t] = b * NPG + gidx;
  }
}

// ---------------- dist rows for selected nodes: D[500][199] ----------------
__global__ void k_dist_rows(const float* __restrict__ out1, const float* __restrict__ out2,
                            const int* __restrict__ sel, float* __restrict__ D) {
  __shared__ float arow[64];
  int i = blockIdx.x;
  int t = threadIdx.x;
  int node = sel[i];
  if (t < 64) arow[t] = out1[(size_t)node * 64 + t];
  __syncthreads();
  float a2 = 0.f;
#pragma unroll
  for (int f = 0; f < 64; f++) a2 = fmaf(arow[f], arow[f], a2);
  for (int nn = t; nn < N2; nn += 256) {
    float dot = 0.f, b2 = 0.f;
#pragma unroll 8
    for (int f = 0; f < 64; f++) {
      float bv = out2[nn * 64 + f];
      dot = fmaf(arow[f], bv, dot);
      b2 = fmaf(bv, bv, b2);
    }
    float d2 = a2 + b2 - 2.f * dot;
    D[i * N2 + nn] = sqrtf(fmaxf(d2, 0.f));
  }
}

// ---------------- fc1 dot ----------------
__global__ void k_fc1_dot(const float* __restrict__ D, const float* __restrict__ w,
                          float* __restrict__ h1pre) {
  constexpr int M = KSEL * N2;
  constexpr int M2 = M / 2;
  int b = blockIdx.x >> 7;
  int j = blockIdx.x & 127;
  int t = threadIdx.x;
  const float2* wp = (const float2*)(w + (size_t)j * M);
  const float2* dp = (const float2*)(D + (size_t)b * M);
  float acc = 0.f;
  for (int m = t; m < M2; m += 256) {
    float2 wv = wp[m];
    float2 dv = dp[m];
    acc = fmaf(dv.x, wv.x, acc);
    acc = fmaf(dv.y, wv.y, acc);
  }
  for (int off = 32; off; off >>= 1) acc += __shfl_xor(acc, off);
  __shared__ float ws_[4];
  int lane = t & 63, wv_ = t >> 6;
  if (lane == 0) ws_[wv_] = acc;
  __syncthreads();
  if (t == 0) h1pre[b * 128 + j] = ws_[0] + ws_[1] + ws_[2] + ws_[3];
}

// ---------------- fused: fc1 bias+LN+relu, fc2+LN+relu, fc3+sigmoid ----------------
__global__ void k_fc123(const float* __restrict__ h1pre, const float* __restrict__ fc1b,
                        const float* __restrict__ g1, const float* __restrict__ be1,
                        const float* __restrict__ w2, const float* __restrict__ b2v,
                        const float* __restrict__ g2, const float* __restrict__ be2,
                        const float* __restrict__ w3, const float* __restrict__ b3,
                        float* __restrict__ out) {
  __shared__ float wsum[2];
  __shared__ float sh[128];
  int b = blockIdx.x, t = threadIdx.x;  // 128
  float acc = h1pre[b * 128 + t] + fc1b[t];
  int lane = t & 63, wv_ = t >> 6;
  float ssum = acc;
  for (int off = 32; off; off >>= 1) ssum += __shfl_xor(ssum, off);
  if (lane == 0) wsum[wv_] = ssum;
  __syncthreads();
  float mu = (wsum[0] + wsum[1]) / 128.f;
  __syncthreads();
  float d = acc - mu;
  float vv = d * d;
  for (int off = 32; off; off >>= 1) vv += __shfl_xor(vv, off);
  if (lane == 0) wsum[wv_] = vv;
  __syncthreads();
  float var = (wsum[0] + wsum[1]) / 128.f;
  float r = rsqrtf(var + LN_EPS);
  float h = d * r * g1[t] + be1[t];
  sh[t] = h > 0.f ? h : 0.f;
  __syncthreads();
  if (t < 64) {
    float a2 = b2v[t];
#pragma unroll 8
    for (int k = 0; k < 128; k++) a2 = fmaf(sh[k], w2[t * 128 + k], a2);
    float s2 = a2;
    for (int off = 32; off; off >>= 1) s2 += __shfl_xor(s2, off);
    float mu2 = s2 * (1.f / 64.f);
    float d2 = a2 - mu2;
    float vv2 = d2 * d2;
    for (int off = 32; off; off >>= 1) vv2 += __shfl_xor(vv2, off);
    float r2 = rsqrtf(vv2 * (1.f / 64.f) + LN_EPS);
    float h2 = d2 * r2 * g2[t] + be2[t];
    h2 = h2 > 0.f ? h2 : 0.f;
    float pp = h2 * w3[t];
    for (int off = 32; off; off >>= 1) pp += __shfl_xor(pp, off);
    if (t == 0) out[b] = 1.f / (1.f + expf(-(pp + b3[0])));
  }
}

extern "C" void kernel_launch(void* const* d_in, const int* in_sizes, int n_in,
                              void* d_out, int out_size, void* d_ws, size_t ws_size,
                              hipStream_t stream) {
  const float* x1 = (const float*)d_in[0];
  const int* ei1 = (const int*)d_in[1];
  const float* x2 = (const float*)d_in[3];
  const int* ei2 = (const int*)d_in[4];
  const float* w1l = (const float*)d_in[5];
  const float* b1l = (const float*)d_in[6];
  const float* w1r = (const float*)d_in[7];
  const float* w2l = (const float*)d_in[8];
  const float* b2l = (const float*)d_in[9];
  const float* w2r = (const float*)d_in[10];
  const float* fc1w = (const float*)d_in[11];
  const float* fc1b = (const float*)d_in[12];
  const float* ln1g = (const float*)d_in[13];
  const float* ln1b = (const float*)d_in[14];
  const float* fc2w = (const float*)d_in[15];
  const float* fc2b = (const float*)d_in[16];
  const float* ln2g = (const float*)d_in[17];
  const float* ln2b = (const float*)d_in[18];
  const float* fc3w = (const float*)d_in[19];
  const float* fc3b = (const float*)d_in[20];
  float* out = (float*)d_out;

  char* p = (char*)d_ws;
  auto alloc = [&](size_t bytes) {
    char* r = p;
    p += (bytes + 255) & ~(size_t)255;
    return r;
  };
  int* rp1 = (int*)alloc((N1 + 1) * 4);
  int* bcnt = (int*)alloc(NB * 4);
  unsigned int* bed = (unsigned int*)alloc((size_t)NB * BCAP * 4);
  int* srcs1 = (int*)alloc((size_t)E1 * 4);
  int* rp2 = (int*)alloc((N2 + 1) * 4);
  int* srcs2 = (int*)alloc(E2 * 4);
  float* bufMean = (float*)alloc((size_t)N1 * 128 * 4);  // reused as zlr (g1)
  float* bufH = (float*)alloc((size_t)N1 * 128 * 4);
  float* out1b = (float*)alloc((size_t)N1 * 64 * 4);
  float* mean2 = (float*)alloc((size_t)N2 * 128 * 4);    // reused as zlr (g2)
  float* h2g = (float*)alloc((size_t)N2 * 128 * 4);
  float* out2b = (float*)alloc((size_t)N2 * 64 * 4);
  int* sel = (int*)alloc(Bg * KSEL * 4);
  ull* cand = (ull*)alloc((size_t)Bg * CHUNKS * KSEL * 8);
  float* Dm = (float*)alloc((size_t)Bg * KSEL * N2 * 4);
  float* h1pre = (float*)alloc(Bg * 128 * 4);

  const int nEdgeBlocks = (E1 + EBT - 1) / EBT;
  const int aggrBlocksA = (N1 + 3) / 4;
  const int aggrBlocksB = (N2 + 3) / 4;
  const int gemmBlocksA = (N1 + 127) / 128;
  const int gemmBlocksB = (N2 + 127) / 128;

  // ---- CSR build (bucketed; graph2 rides as extra block) ----
  hipMemsetAsync(bcnt, 0, NB * 4, stream);
  k_bucket<<<nEdgeBlocks + 1, 256, 0, stream>>>(ei1, bcnt, bed, ei2, rp2, srcs2);
  k_csr_bucket<<<NB, 1024, 0, stream>>>(bcnt, bed, rp1, srcs1);
  // ---- GNN (both graphs per launch) ----
  k_aggr128<<<aggrBlocksA + aggrBlocksB, 256, 0, stream>>>(
      x1, rp1, srcs1, bufMean, N1, x2, rp2, srcs2, mean2, N2, aggrBlocksA);
  k_sage_gemm128<<<gemmBlocksA + gemmBlocksB, 256, 0, stream>>>(
      x1, bufMean, bufH, N1, x2, mean2, h2g, N2, w1l, b1l, w1r, gemmBlocksA);
  k_lin_dual<<<gemmBlocksA + gemmBlocksB, 256, 0, stream>>>(
      bufH, bufMean, N1, h2g, mean2, N2, w2l, w2r, gemmBlocksA);
  k_aggr_fused64<<<aggrBlocksA + aggrBlocksB, 256, 0, stream>>>(
      bufMean, rp1, srcs1, out1b, N1, mean2, rp2, srcs2, out2b, N2, b2l, aggrBlocksA);
  // ---- head ----
  k_score_topk_local<<<Bg * CHUNKS, 256, 0, stream>>>(out1b, out2b, cand);
  k_topk_merge<<<Bg, 256, 0, stream>>>(cand, sel);
  k_dist_rows<<<Bg * KSEL, 256, 0, stream>>>(out1b, out2b, sel, Dm);
  k_fc1_dot<<<Bg * 128, 256, 0, stream>>>(Dm, fc1w, h1pre);
  k_fc123<<<Bg, 128, 0, stream>>>(h1pre, fc1b, ln1g, ln1b, fc2w, fc2b, ln2g, ln2b,
                                  fc3w, fc3b, out);
}